// Round 12
// baseline (1505.487 us; speedup 1.0000x reference)
//
#include <hip/hip_runtime.h>

typedef _Float16 half8 __attribute__((ext_vector_type(8)));
typedef _Float16 half4 __attribute__((ext_vector_type(4)));
typedef float    f32x4 __attribute__((ext_vector_type(4)));

#define N_NODES 65536
#define N_EDGES 131072
#define BB      2048
#define HDIM    300
#define HPAD    320   // K padded to multiple of 32

// ---------------- prepack: dst[384][Kpad] = W[k][n]  (B^T panel, zero-padded)
__global__ __launch_bounds__(256) void prepack_w(const float* __restrict__ src,
                                                 _Float16* __restrict__ dst,
                                                 int Kpad, int Kreal) {
    int idx = blockIdx.x * 256 + threadIdx.x;
    int n = idx / Kpad, k = idx - n * Kpad;
    if (n >= 384) return;
    float v = (n < 300 && k < Kreal) ? src[k * 300 + n] : 0.f;
    dst[idx] = (_Float16)v;
}

__global__ __launch_bounds__(256) void cvt_x(const float* __restrict__ x,
                                             _Float16* __restrict__ xh, int n) {
    int i = blockIdx.x * 256 + threadIdx.x;
    if (i < n) xh[i] = (_Float16)x[i];
}

// edge feats -> f16, permuted into CSR order, zero-padded to 32 cols
__global__ __launch_bounds__(256) void cvt_e_csr(const float* __restrict__ ein,
                                                 const int2* __restrict__ se,
                                                 _Float16* __restrict__ ecsr) {
    int i = blockIdx.x * 256 + threadIdx.x;
    if (i >= N_EDGES * 32) return;
    int k = i & 31, s = i >> 5;
    int e = se[s].y;
    ecsr[i] = (_Float16)(k < 16 ? ein[(size_t)e * 16 + k] : 0.f);
}

__device__ __forceinline__ void gload16(const _Float16* g, _Float16* l) {
    __builtin_amdgcn_global_load_lds(
        (const __attribute__((address_space(1))) void*)g,
        (__attribute__((address_space(3))) void*)l, 16, 0, 0);
}

// ---------------- MFMA GEMM (node-proj K=64 / edge-proj K=32)
// Bp is [384][K] f16. 128x128 tile, 4 waves, 64x64/wave.
template <bool RELU>
__global__ __launch_bounds__(256) void gemm_f16(
        const _Float16* __restrict__ A,
        const _Float16* __restrict__ Bp, const float* __restrict__ bias,
        _Float16* __restrict__ out, int M, int K) {
    __shared__ _Float16 lds[3][2][128 * 32];   // [buf][A/B][row*32+k] : 48 KB

    int bid = blockIdx.x;
    int xcd = bid & 7, grp = bid >> 3;
    int mt = xcd + 8 * (grp / 3);
    int nt = grp % 3;
    int m0 = mt * 128, n0 = nt * 128;
    int t = threadIdx.x;
    int lane = t & 63, w = t >> 6;
    int wr = w >> 1, wc = w & 1;

    int srow[2], sko[2];
    #pragma unroll
    for (int q = 0; q < 2; ++q) {
        int row = (w * 2 + q) * 16 + (lane >> 2);
        int ch = (lane & 3) ^ ((row >> 1) & 3);
        srow[q] = row; sko[q] = ch * 8;
    }

    f32x4 acc[4][4] = {};
    int NK = K >> 5;

    auto stage = [&](int buf, int k0) {
        #pragma unroll
        for (int q = 0; q < 2; ++q) {
            gload16(&A[(size_t)(m0 + srow[q]) * K + k0 + sko[q]], &lds[buf][0][(w * 2 + q) * 512]);
            gload16(&Bp[(size_t)(n0 + srow[q]) * K + k0 + sko[q]], &lds[buf][1][(w * 2 + q) * 512]);
        }
    };

    stage(0, 0);
    if (NK > 1) stage(1, 32);
    for (int kt = 0; kt < NK; ++kt) {
        int cur = kt % 3;
        if (kt + 1 < NK) {
            asm volatile("s_waitcnt vmcnt(4)" ::: "memory");
        } else {
            asm volatile("s_waitcnt vmcnt(0)" ::: "memory");
        }
        __builtin_amdgcn_s_barrier();
        __builtin_amdgcn_sched_barrier(0);
        if (kt + 2 < NK) stage((kt + 2) % 3, (kt + 2) << 5);

        int lr = lane & 15, hi = lane >> 4;
        half8 af[4], bf[4];
        #pragma unroll
        for (int i = 0; i < 4; ++i) {
            int row = wr * 64 + i * 16 + lr;
            int lk = (hi ^ ((row >> 1) & 3)) * 8;
            af[i] = *(const half8*)&lds[cur][0][row * 32 + lk];
        }
        #pragma unroll
        for (int j = 0; j < 4; ++j) {
            int row = wc * 64 + j * 16 + lr;
            int lk = (hi ^ ((row >> 1) & 3)) * 8;
            bf[j] = *(const half8*)&lds[cur][1][row * 32 + lk];
        }
        #pragma unroll
        for (int i = 0; i < 4; ++i)
            #pragma unroll
            for (int j = 0; j < 4; ++j)
                acc[i][j] = __builtin_amdgcn_mfma_f32_16x16x32_f16(af[i], bf[j], acc[i][j], 0, 0, 0);
    }
    __syncthreads();

    _Float16* ct = &lds[0][0][0];
    {
        int lr = lane & 15, lq = (lane >> 4) * 4;
        #pragma unroll
        for (int j = 0; j < 4; ++j) {
            int col = wc * 64 + j * 16 + lr;
            int gcol = n0 + col;
            float bv = (gcol < 300) ? bias[gcol] : 0.f;
            #pragma unroll
            for (int i = 0; i < 4; ++i) {
                int rbase = wr * 64 + i * 16 + lq;
                #pragma unroll
                for (int q = 0; q < 4; ++q) {
                    float v = acc[i][j][q] + bv;
                    if (RELU) v = v > 0.f ? v : 0.f;
                    if (gcol >= 300) v = 0.f;
                    ct[(rbase + q) * 128 + col] = (_Float16)v;
                }
            }
        }
    }
    __syncthreads();
    #pragma unroll
    for (int r = 0; r < 8; ++r) {
        int row = r * 16 + (t >> 4);
        int c8 = (t & 15) * 8;
        if (n0 + c8 < HPAD) {
            half8 v = *(const half8*)&ct[row * 128 + c8];
            *(half8*)&out[(size_t)(m0 + row) * HPAD + n0 + c8] = v;
        }
    }
}

// ---------------- fused layer v3: out = (relu(z@W1+b1))@W2 + b2 (+relu)
// 64-row band, 512 thr = 8 waves (2M x 4N), wave-tile 32x80: acc[2][5]=40 VGPR.
// Phase 1: z staged via global_load_lds (BK=64, 3-buf, counted vmcnt(1), single
// barrier), B=W1 from L2. t -> LDS (chunk-XOR swizzle). Phase 2: A from t-LDS,
// B=W2 from L2. LDS 64 KB -> 2 blocks/CU. Epilogue via LDS, coalesced stores.
__global__ __launch_bounds__(512) void fused_layer(
        const _Float16* __restrict__ z, const _Float16* __restrict__ W1p,
        const float* __restrict__ b1, const _Float16* __restrict__ W2p,
        const float* __restrict__ b2, _Float16* __restrict__ out, int lastrelu) {
    __shared__ _Float16 zst[3][64 * 64];   // 24 KB z staging
    __shared__ _Float16 tl[64 * 320];      // 40 KB t tile
    int m0 = blockIdx.x * 64;
    int t = threadIdx.x;
    int lane = t & 63, w = t >> 6;
    int wr = w >> 2, wcn = (w & 3) * 80;   // wave M-half (32 rows), N-base
    int lr = lane & 15, hi = lane >> 4;

    // staging geometry: wave w stages rows w*8..w*8+7 (1 gload16/thread/stage)
    int srow = w * 8 + (lane >> 3);
    int sch  = (lane & 7) ^ (srow & 7);    // pre-swizzled source chunk
    const _Float16* zsrc = &z[(size_t)(m0 + srow) * HPAD + sch * 8];

    f32x4 acc[2][5];
    #pragma unroll
    for (int i = 0; i < 2; ++i)
        #pragma unroll
        for (int j = 0; j < 5; ++j) acc[i][j] = (f32x4){0.f, 0.f, 0.f, 0.f};

    auto stage = [&](int buf, int ks) {
        gload16(zsrc + ks * 64, &zst[buf][w * 512]);
    };

    // ---- phase 1: acc = z @ W1 (5 K-steps of 64) ----
    stage(0, 0);
    stage(1, 1);
    #pragma unroll 1
    for (int ks = 0; ks < 5; ++ks) {
        int cur = ks % 3;
        if (ks + 1 < 5) {
            asm volatile("s_waitcnt vmcnt(1)" ::: "memory");   // my stage(ks) landed
        } else {
            asm volatile("s_waitcnt vmcnt(0)" ::: "memory");
        }
        __builtin_amdgcn_s_barrier();
        __builtin_amdgcn_sched_barrier(0);
        if (ks + 2 < 5) stage((ks + 2) % 3, ks + 2);

        #pragma unroll
        for (int kk = 0; kk < 2; ++kk) {
            half8 af[2], bf[5];
            #pragma unroll
            for (int i = 0; i < 2; ++i) {
                int row = wr * 32 + i * 16 + lr;
                int c = kk * 4 + hi;
                af[i] = *(const half8*)&zst[cur][row * 64 + ((c ^ (row & 7)) << 3)];
            }
            #pragma unroll
            for (int j = 0; j < 5; ++j)
                bf[j] = *(const half8*)&W1p[(size_t)(wcn + j * 16 + lr) * HPAD + ks * 64 + kk * 32 + hi * 8];
            #pragma unroll
            for (int i = 0; i < 2; ++i)
                #pragma unroll
                for (int j = 0; j < 5; ++j)
                    acc[i][j] = __builtin_amdgcn_mfma_f32_16x16x32_f16(af[i], bf[j], acc[i][j], 0, 0, 0);
        }
    }
    // t = relu(acc + b1) -> tl (chunk-XOR swizzle: c' = c ^ (row&7))
    #pragma unroll
    for (int j = 0; j < 5; ++j) {
        int col = wcn + j * 16 + lr;
        float bv = (col < 300) ? b1[col] : 0.f;
        #pragma unroll
        for (int i = 0; i < 2; ++i) {
            int rbase = wr * 32 + i * 16 + hi * 4;
            #pragma unroll
            for (int q = 0; q < 4; ++q) {
                float v = acc[i][j][q] + bv;
                v = v > 0.f ? v : 0.f;
                int row = rbase + q;
                tl[row * 320 + ((((col >> 3) ^ (row & 7)) << 3) | (col & 7))] = (_Float16)v;
            }
        }
    }
    __syncthreads();

    // ---- phase 2: acc = t @ W2 ----
    #pragma unroll
    for (int i = 0; i < 2; ++i)
        #pragma unroll
        for (int j = 0; j < 5; ++j) acc[i][j] = (f32x4){0.f, 0.f, 0.f, 0.f};
    #pragma unroll 2
    for (int kt = 0; kt < 10; ++kt) {
        half8 af[2], bf[5];
        #pragma unroll
        for (int i = 0; i < 2; ++i) {
            int row = wr * 32 + i * 16 + lr;
            int c = kt * 4 + hi;
            af[i] = *(const half8*)&tl[row * 320 + ((c ^ (row & 7)) << 3)];
        }
        #pragma unroll
        for (int j = 0; j < 5; ++j)
            bf[j] = *(const half8*)&W2p[(size_t)(wcn + j * 16 + lr) * HPAD + kt * 32 + hi * 8];
        #pragma unroll
        for (int i = 0; i < 2; ++i)
            #pragma unroll
            for (int j = 0; j < 5; ++j)
                acc[i][j] = __builtin_amdgcn_mfma_f32_16x16x32_f16(af[i], bf[j], acc[i][j], 0, 0, 0);
    }
    __syncthreads();   // all waves done reading t

    // epilogue: acc + b2 (+relu), pad cols zeroed, -> tl -> coalesced store
    #pragma unroll
    for (int j = 0; j < 5; ++j) {
        int col = wcn + j * 16 + lr;
        float bv = (col < 300) ? b2[col] : 0.f;
        #pragma unroll
        for (int i = 0; i < 2; ++i) {
            int rbase = wr * 32 + i * 16 + hi * 4;
            #pragma unroll
            for (int q = 0; q < 4; ++q) {
                float v = acc[i][j][q] + bv;
                if (lastrelu) v = v > 0.f ? v : 0.f;
                if (col >= 300) v = 0.f;
                int row = rbase + q;
                tl[row * 320 + ((((col >> 3) ^ (row & 7)) << 3) | (col & 7))] = (_Float16)v;
            }
        }
    }
    __syncthreads();
    #pragma unroll
    for (int r = 0; r < 5; ++r) {
        int idx = r * 512 + t;
        int row = idx / 40, c = idx - row * 40;
        half8 v = *(const half8*)&tl[row * 320 + ((c ^ (row & 7)) << 3)];
        *(half8*)&out[(size_t)(m0 + row) * HPAD + c * 8] = v;
    }
}

// ---------------- CSR build (natural node order) ----------------
__global__ __launch_bounds__(256) void hist_kernel(const int* __restrict__ dst,
                                                   int* __restrict__ counts) {
    int e = blockIdx.x * 256 + threadIdx.x;
    if (e < N_EDGES) atomicAdd(&counts[dst[e]], 1);
}

__global__ __launch_bounds__(256) void scan_block(const int* __restrict__ in,
                                                  int* __restrict__ partial,
                                                  int* __restrict__ bsum, int nb) {
    __shared__ int s[256];
    int b = blockIdx.x, t = threadIdx.x;
    int v = (b < nb) ? in[b * 256 + t] : 0;
    s[t] = v;
    __syncthreads();
    for (int o = 1; o < 256; o <<= 1) {
        int x = (t >= o) ? s[t - o] : 0;
        __syncthreads();
        s[t] += x;
        __syncthreads();
    }
    partial[b * 256 + t] = s[t] - v;      // exclusive
    if (t == 255 && bsum) bsum[b] = s[255];
}

__global__ __launch_bounds__(256) void add_offsets(const int* __restrict__ partial,
                                                   const int* __restrict__ boff,
                                                   int* __restrict__ rowptr) {
    int i = blockIdx.x * 256 + threadIdx.x;
    if (i < N_NODES) rowptr[i] = partial[i] + boff[i >> 8];
    if (i == 0) rowptr[N_NODES] = N_EDGES;
}

__global__ __launch_bounds__(256) void scatter_csr(const int* __restrict__ src,
                                                   const int* __restrict__ dst,
                                                   const int* __restrict__ rowptr,
                                                   int* __restrict__ cnt,
                                                   int2* __restrict__ se) {
    int e = blockIdx.x * 256 + threadIdx.x;
    if (e >= N_EDGES) return;
    int d = dst[e];
    int pos = atomicAdd(&cnt[d], 1);
    se[rowptr[d] + pos] = make_int2(src[e], e);
}

// ---------------- gather: z[d] = h[d] + sum_{s in row(d)} relu(h[src_s] + ehcsr[s])
__global__ __launch_bounds__(320) void gather_z(
        const _Float16* __restrict__ h, const _Float16* __restrict__ ehcsr,
        const int2* __restrict__ se, const int* __restrict__ rowptr,
        _Float16* __restrict__ z, int nblocks) {
    int t = threadIdx.x;
    int c = t % 40, ns = t / 40;
    for (int node = blockIdx.x * 8 + ns; node < N_NODES; node += nblocks * 8) {
        int r0 = rowptr[node], r1 = rowptr[node + 1];
        half8 hn = *(const half8*)&h[(size_t)node * HPAD + c * 8];
        half8 acc = {};
        for (int s = r0; s < r1; s += 4) {
            int nb = r1 - s;
            int idx[4];
            idx[0] = s;
            idx[1] = s + (1 < nb ? 1 : 0);
            idx[2] = s + (2 < nb ? 2 : 0);
            idx[3] = s + (3 < nb ? 3 : 0);
            half8 hv[4], ev[4];
            #pragma unroll
            for (int u = 0; u < 4; ++u) {
                int sp = se[idx[u]].x;
                hv[u] = *(const half8*)&h[(size_t)sp * HPAD + c * 8];
                ev[u] = *(const half8*)&ehcsr[(size_t)idx[u] * HPAD + c * 8];
            }
            #pragma unroll
            for (int u = 0; u < 4; ++u) {
                half8 m = hv[u] + ev[u];
                #pragma unroll
                for (int j = 0; j < 8; ++j)
                    m[j] = m[j] > (_Float16)0 ? m[j] : (_Float16)0;
                if (u < nb) acc += m;
            }
        }
        half8 o = hn + acc;          // pad cols: 0 + 0 = 0
        *(half8*)&z[(size_t)node * HPAD + c * 8] = o;
    }
}

// ---------------- per-molecule sum pool (32 consecutive rows)
__global__ __launch_bounds__(128) void pool_kernel(const _Float16* __restrict__ h,
                                                   float* __restrict__ out, int add) {
    int b = blockIdx.x, t = threadIdx.x;
    if (t >= 75) return;
    float a0 = 0, a1 = 0, a2 = 0, a3 = 0;
    for (int r = 0; r < 32; ++r) {
        half4 v = *(const half4*)&h[(size_t)(b * 32 + r) * HPAD + t * 4];
        a0 += (float)v[0]; a1 += (float)v[1]; a2 += (float)v[2]; a3 += (float)v[3];
    }
    f32x4 o = {a0, a1, a2, a3};
    if (add) o += *(f32x4*)&out[b * 300 + t * 4];
    *(f32x4*)&out[b * 300 + t * 4] = o;
}

__global__ __launch_bounds__(256) void diff_kernel(float* __restrict__ reaction,
                                                   const float* __restrict__ reactants,
                                                   const float* __restrict__ products, int n) {
    int i = blockIdx.x * 256 + threadIdx.x;
    if (i < n) reaction[i] = reactants[i] - products[i];
}

extern "C" void kernel_launch(void* const* d_in, const int* in_sizes, int n_in,
                              void* d_out, int out_size, void* d_ws, size_t ws_size,
                              hipStream_t stream) {
    const float* x[3]   = {(const float*)d_in[0], (const float*)d_in[5],  (const float*)d_in[10]};
    const float* ein[3] = {(const float*)d_in[1], (const float*)d_in[6],  (const float*)d_in[11]};
    const int*   src[3] = {(const int*)d_in[2],   (const int*)d_in[7],    (const int*)d_in[12]};
    const int*   dst[3] = {(const int*)d_in[3],   (const int*)d_in[8],    (const int*)d_in[13]};
    const float* Wn = (const float*)d_in[15];
    const float* bn = (const float*)d_in[16];
    const float* We = (const float*)d_in[17];
    const float* be = (const float*)d_in[18];
    const float* W1 = (const float*)d_in[19];
    const float* b1 = (const float*)d_in[20];
    const float* W2 = (const float*)d_in[21];
    const float* b2 = (const float*)d_in[22];

    char* ws = (char*)d_ws;
    size_t off = 0;
    auto alloc = [&](size_t bytes) {
        char* p = ws + off; off += (bytes + 1023) & ~(size_t)1023; return p;
    };
    _Float16* h     = (_Float16*)alloc((size_t)N_NODES * HPAD * 2);   // 40 MiB
    _Float16* zbuf  = (_Float16*)alloc((size_t)N_NODES * HPAD * 2);   // 40 MiB
    _Float16* tbuf  = (_Float16*)alloc((size_t)N_NODES * HPAD * 2);   // 40 MiB (ecsr host)
    _Float16* ehcsr = (_Float16*)alloc((size_t)N_EDGES * HPAD * 2);   // 80 MiB
    int*      counts= (int*)alloc((size_t)N_NODES * 4);               // \ contiguous
    int*      cnt   = (int*)alloc((size_t)N_NODES * 4);               // /  memset pair
    int*      part  = (int*)alloc((size_t)N_NODES * 4);
    int*      bsum  = (int*)alloc(256 * 4);
    int*      bpart = (int*)alloc(256 * 4);
    int*      bzero = (int*)alloc(4);
    int*      rowptr= (int*)alloc((size_t)(N_NODES + 1) * 4);
    int2*     se    = (int2*)alloc((size_t)N_EDGES * 8);
    _Float16* Wt1   = (_Float16*)alloc((size_t)3 * 384 * HPAD * 2);
    _Float16* Wt2   = (_Float16*)alloc((size_t)3 * 384 * HPAD * 2);
    _Float16* Wnt   = (_Float16*)alloc((size_t)384 * 64 * 2);
    _Float16* Wet   = (_Float16*)alloc((size_t)384 * 32 * 2);
    // overlays (both dead before their hosts are written):
    _Float16* xh    = (_Float16*)zbuf;   // consumed by node-proj GEMM before gather writes zbuf
    _Float16* ecsr  = (_Float16*)tbuf;   // consumed by eh-GEMM; tbuf otherwise unused now

    if (off > ws_size) return;   // graceful diagnostic failure if ws too small

    for (int l = 0; l < 3; ++l) {
        prepack_w<<<(384 * HPAD + 255) / 256, 256, 0, stream>>>(W1 + l * 90000, Wt1 + l * 384 * HPAD, HPAD, 300);
        prepack_w<<<(384 * HPAD + 255) / 256, 256, 0, stream>>>(W2 + l * 90000, Wt2 + l * 384 * HPAD, HPAD, 300);
    }
    prepack_w<<<(384 * 64 + 255) / 256, 256, 0, stream>>>(Wn, Wnt, 64, 64);
    prepack_w<<<(384 * 32 + 255) / 256, 256, 0, stream>>>(We, Wet, 32, 16);
    hipMemsetAsync(bzero, 0, 4, stream);

    float* outp      = (float*)d_out;
    float* reaction  = outp;
    float* reactants = outp + (size_t)BB * HDIM;
    float* products  = outp + (size_t)2 * BB * HDIM;

    const int EG = (N_EDGES + 255) / 256;
    for (int g = 0; g < 3; ++g) {
        // node projection: h = relu(x @ Wn + bn)
        cvt_x<<<(N_NODES * 64 + 255) / 256, 256, 0, stream>>>(x[g], xh, N_NODES * 64);
        gemm_f16<true><<<512 * 3, 256, 0, stream>>>(xh, Wnt, bn, h, N_NODES, 64);

        // CSR build (incoming edges per node), natural node order
        hipMemsetAsync(counts, 0, (size_t)2 * N_NODES * 4, stream);   // counts + cnt
        hist_kernel<<<EG, 256, 0, stream>>>(dst[g], counts);
        scan_block<<<256, 256, 0, stream>>>(counts, part, bsum, 256);
        scan_block<<<1, 256, 0, stream>>>(bsum, bpart, bzero, 1);
        add_offsets<<<256, 256, 0, stream>>>(part, bpart, rowptr);
        scatter_csr<<<EG, 256, 0, stream>>>(src[g], dst[g], rowptr, cnt, se);

        // edge projection once per graph, in CSR order: ehcsr = ecsr @ We + be
        cvt_e_csr<<<(N_EDGES * 32 + 255) / 256, 256, 0, stream>>>(ein[g], se, ecsr);
        gemm_f16<false><<<1024 * 3, 256, 0, stream>>>(ecsr, Wet, be, ehcsr, N_EDGES, 32);

        for (int l = 0; l < 3; ++l) {
            gather_z<<<2048, 320, 0, stream>>>(h, ehcsr, se, rowptr, zbuf, 2048);
            // h = fused MLP(z) : relu(z@W1+b1)@W2+b2 (+relu if l<2)
            fused_layer<<<1024, 512, 0, stream>>>(zbuf, Wt1 + l * 384 * HPAD, b1 + l * 300,
                                                  Wt2 + l * 384 * HPAD, b2 + l * 300, h, l < 2);
        }
        if (g == 0)      pool_kernel<<<BB, 128, 0, stream>>>(h, reactants, 0);
        else if (g == 1) pool_kernel<<<BB, 128, 0, stream>>>(h, reactants, 1);
        else             pool_kernel<<<BB, 128, 0, stream>>>(h, products, 0);
    }
    diff_kernel<<<((BB * HDIM) + 255) / 256, 256, 0, stream>>>(reaction, reactants, products, BB * HDIM);
}

// Round 13
// 1253.032 us; speedup vs baseline: 1.2015x; 1.2015x over previous
//
#include <hip/hip_runtime.h>

typedef _Float16 half8 __attribute__((ext_vector_type(8)));
typedef _Float16 half4 __attribute__((ext_vector_type(4)));
typedef float    f32x4 __attribute__((ext_vector_type(4)));

#define N_NODES 65536
#define N_EDGES 131072
#define BB      2048
#define HDIM    300
#define HPAD    320   // K padded to multiple of 32

// ---------------- prepack: dst[384][Kpad] = W[k][n]  (B^T panel, zero-padded)
__global__ __launch_bounds__(256) void prepack_w(const float* __restrict__ src,
                                                 _Float16* __restrict__ dst,
                                                 int Kpad, int Kreal) {
    int idx = blockIdx.x * 256 + threadIdx.x;
    int n = idx / Kpad, k = idx - n * Kpad;
    if (n >= 384) return;
    float v = (n < 300 && k < Kreal) ? src[k * 300 + n] : 0.f;
    dst[idx] = (_Float16)v;
}

__global__ __launch_bounds__(256) void cvt_x(const float* __restrict__ x,
                                             _Float16* __restrict__ xh, int n) {
    int i = blockIdx.x * 256 + threadIdx.x;
    if (i < n) xh[i] = (_Float16)x[i];
}

// edge feats -> f16, permuted into CSR order, zero-padded to 32 cols
__global__ __launch_bounds__(256) void cvt_e_csr(const float* __restrict__ ein,
                                                 const int2* __restrict__ se,
                                                 _Float16* __restrict__ ecsr) {
    int i = blockIdx.x * 256 + threadIdx.x;
    if (i >= N_EDGES * 32) return;
    int k = i & 31, s = i >> 5;
    int e = se[s].y;
    ecsr[i] = (_Float16)(k < 16 ? ein[(size_t)e * 16 + k] : 0.f);
}

__device__ __forceinline__ void gload16(const _Float16* g, _Float16* l) {
    __builtin_amdgcn_global_load_lds(
        (const __attribute__((address_space(1))) void*)g,
        (__attribute__((address_space(3))) void*)l, 16, 0, 0);
}

// ---------------- MFMA GEMM: out[M][320] = op( A[M][K] @ Bp^T ) + bias
// Bp is [384][K] f16. 128x128 tile, 4 waves, 64x64/wave.
// global_load_lds staging, 3-buf, single barrier/iter, counted vmcnt,
// XOR-swizzled LDS, XCD-grouped blocks, LDS-transposed coalesced epilogue.
// nt==2 trim: wc==1 waves' cols (320..383) are all pad -> skip their compute.
template <bool RELU>
__global__ __launch_bounds__(256) void gemm_f16(
        const _Float16* __restrict__ A,
        const _Float16* __restrict__ Bp, const float* __restrict__ bias,
        _Float16* __restrict__ out, int M, int K) {
    __shared__ _Float16 lds[3][2][128 * 32];   // [buf][A/B][row*32+k] : 48 KB

    // XCD grouping: the 3 nt-siblings of one mt land on the same XCD (bid%8)
    int bid = blockIdx.x;
    int xcd = bid & 7, grp = bid >> 3;
    int mt = xcd + 8 * (grp / 3);
    int nt = grp % 3;
    int m0 = mt * 128, n0 = nt * 128;
    int t = threadIdx.x;
    int lane = t & 63, w = t >> 6;
    int wr = w >> 1, wc = w & 1;
    bool deadwave = (nt == 2) && (wc == 1);   // all 64 cols >= 320 (pad): skip compute

    int srow[2], sko[2];
    #pragma unroll
    for (int q = 0; q < 2; ++q) {
        int row = (w * 2 + q) * 16 + (lane >> 2);
        int ch = (lane & 3) ^ ((row >> 1) & 3);
        srow[q] = row; sko[q] = ch * 8;
    }

    f32x4 acc[4][4] = {};
    int NK = K >> 5;

    auto stage = [&](int buf, int k0) {
        #pragma unroll
        for (int q = 0; q < 2; ++q) {
            gload16(&A[(size_t)(m0 + srow[q]) * K + k0 + sko[q]], &lds[buf][0][(w * 2 + q) * 512]);
            gload16(&Bp[(size_t)(n0 + srow[q]) * K + k0 + sko[q]], &lds[buf][1][(w * 2 + q) * 512]);
        }
    };

    stage(0, 0);
    if (NK > 1) stage(1, 32);
    for (int kt = 0; kt < NK; ++kt) {
        int cur = kt % 3;
        if (kt + 1 < NK) {
            asm volatile("s_waitcnt vmcnt(4)" ::: "memory");   // stage kt landed
        } else {
            asm volatile("s_waitcnt vmcnt(0)" ::: "memory");
        }
        __builtin_amdgcn_s_barrier();
        __builtin_amdgcn_sched_barrier(0);
        if (kt + 2 < NK) stage((kt + 2) % 3, (kt + 2) << 5);

        if (!deadwave) {
            int lr = lane & 15, hi = lane >> 4;
            half8 af[4], bf[4];
            #pragma unroll
            for (int i = 0; i < 4; ++i) {
                int row = wr * 64 + i * 16 + lr;
                int lk = (hi ^ ((row >> 1) & 3)) * 8;
                af[i] = *(const half8*)&lds[cur][0][row * 32 + lk];
            }
            #pragma unroll
            for (int j = 0; j < 4; ++j) {
                int row = wc * 64 + j * 16 + lr;
                int lk = (hi ^ ((row >> 1) & 3)) * 8;
                bf[j] = *(const half8*)&lds[cur][1][row * 32 + lk];
            }
            #pragma unroll
            for (int i = 0; i < 4; ++i)
                #pragma unroll
                for (int j = 0; j < 4; ++j)
                    acc[i][j] = __builtin_amdgcn_mfma_f32_16x16x32_f16(af[i], bf[j], acc[i][j], 0, 0, 0);
        }
    }
    __syncthreads();   // protect lds reuse by epilogue

    // epilogue: acc -> LDS (f16, 128x128) -> coalesced 256B stores
    _Float16* ct = &lds[0][0][0];
    if (!deadwave) {
        int lr = lane & 15, lq = (lane >> 4) * 4;
        #pragma unroll
        for (int j = 0; j < 4; ++j) {
            int col = wc * 64 + j * 16 + lr;
            int gcol = n0 + col;
            float bv = (gcol < 300) ? bias[gcol] : 0.f;
            #pragma unroll
            for (int i = 0; i < 4; ++i) {
                int rbase = wr * 64 + i * 16 + lq;
                #pragma unroll
                for (int q = 0; q < 4; ++q) {
                    float v = acc[i][j][q] + bv;
                    if (RELU) v = v > 0.f ? v : 0.f;
                    if (gcol >= 300) v = 0.f;
                    ct[(rbase + q) * 128 + col] = (_Float16)v;
                }
            }
        }
    }
    __syncthreads();
    #pragma unroll
    for (int r = 0; r < 8; ++r) {
        int row = r * 16 + (t >> 4);
        int c8 = (t & 15) * 8;
        if (n0 + c8 < HPAD) {
            half8 v = *(const half8*)&ct[row * 128 + c8];
            *(half8*)&out[(size_t)(m0 + row) * HPAD + n0 + c8] = v;
        }
    }
}

// ---------------- CSR build (natural node order) ----------------
__global__ __launch_bounds__(256) void hist_kernel(const int* __restrict__ dst,
                                                   int* __restrict__ counts) {
    int e = blockIdx.x * 256 + threadIdx.x;
    if (e < N_EDGES) atomicAdd(&counts[dst[e]], 1);
}

__global__ __launch_bounds__(256) void scan_block(const int* __restrict__ in,
                                                  int* __restrict__ partial,
                                                  int* __restrict__ bsum, int nb) {
    __shared__ int s[256];
    int b = blockIdx.x, t = threadIdx.x;
    int v = (b < nb) ? in[b * 256 + t] : 0;
    s[t] = v;
    __syncthreads();
    for (int o = 1; o < 256; o <<= 1) {
        int x = (t >= o) ? s[t - o] : 0;
        __syncthreads();
        s[t] += x;
        __syncthreads();
    }
    partial[b * 256 + t] = s[t] - v;      // exclusive
    if (t == 255 && bsum) bsum[b] = s[255];
}

__global__ __launch_bounds__(256) void add_offsets(const int* __restrict__ partial,
                                                   const int* __restrict__ boff,
                                                   int* __restrict__ rowptr) {
    int i = blockIdx.x * 256 + threadIdx.x;
    if (i < N_NODES) rowptr[i] = partial[i] + boff[i >> 8];
    if (i == 0) rowptr[N_NODES] = N_EDGES;
}

__global__ __launch_bounds__(256) void scatter_csr(const int* __restrict__ src,
                                                   const int* __restrict__ dst,
                                                   const int* __restrict__ rowptr,
                                                   int* __restrict__ cnt,
                                                   int2* __restrict__ se) {
    int e = blockIdx.x * 256 + threadIdx.x;
    if (e >= N_EDGES) return;
    int d = dst[e];
    int pos = atomicAdd(&cnt[d], 1);
    se[rowptr[d] + pos] = make_int2(src[e], e);
}

// ---------------- gather: z[d] = h[d] + sum_{s in row(d)} relu(h[src_s] + ehcsr[s])
// ehcsr in CSR order -> sequential streaming. 320 thr = 8 node-slots x 40 half8.
__global__ __launch_bounds__(320) void gather_z(
        const _Float16* __restrict__ h, const _Float16* __restrict__ ehcsr,
        const int2* __restrict__ se, const int* __restrict__ rowptr,
        _Float16* __restrict__ z, int nblocks) {
    int t = threadIdx.x;
    int c = t % 40, ns = t / 40;
    for (int node = blockIdx.x * 8 + ns; node < N_NODES; node += nblocks * 8) {
        int r0 = rowptr[node], r1 = rowptr[node + 1];
        half8 hn = *(const half8*)&h[(size_t)node * HPAD + c * 8];
        half8 acc = {};
        for (int s = r0; s < r1; s += 4) {
            int nb = r1 - s;
            int idx[4];
            idx[0] = s;
            idx[1] = s + (1 < nb ? 1 : 0);
            idx[2] = s + (2 < nb ? 2 : 0);
            idx[3] = s + (3 < nb ? 3 : 0);
            half8 hv[4], ev[4];
            #pragma unroll
            for (int u = 0; u < 4; ++u) {
                int sp = se[idx[u]].x;
                hv[u] = *(const half8*)&h[(size_t)sp * HPAD + c * 8];
                ev[u] = *(const half8*)&ehcsr[(size_t)idx[u] * HPAD + c * 8];
            }
            #pragma unroll
            for (int u = 0; u < 4; ++u) {
                half8 m = hv[u] + ev[u];
                #pragma unroll
                for (int j = 0; j < 8; ++j)
                    m[j] = m[j] > (_Float16)0 ? m[j] : (_Float16)0;
                if (u < nb) acc += m;
            }
        }
        half8 o = hn + acc;          // pad cols: 0 + 0 = 0
        *(half8*)&z[(size_t)node * HPAD + c * 8] = o;
    }
}

// ---------------- per-molecule sum pool (32 consecutive rows)
__global__ __launch_bounds__(128) void pool_kernel(const _Float16* __restrict__ h,
                                                   float* __restrict__ out, int add) {
    int b = blockIdx.x, t = threadIdx.x;
    if (t >= 75) return;
    float a0 = 0, a1 = 0, a2 = 0, a3 = 0;
    for (int r = 0; r < 32; ++r) {
        half4 v = *(const half4*)&h[(size_t)(b * 32 + r) * HPAD + t * 4];
        a0 += (float)v[0]; a1 += (float)v[1]; a2 += (float)v[2]; a3 += (float)v[3];
    }
    f32x4 o = {a0, a1, a2, a3};
    if (add) o += *(f32x4*)&out[b * 300 + t * 4];
    *(f32x4*)&out[b * 300 + t * 4] = o;
}

__global__ __launch_bounds__(256) void diff_kernel(float* __restrict__ reaction,
                                                   const float* __restrict__ reactants,
                                                   const float* __restrict__ products, int n) {
    int i = blockIdx.x * 256 + threadIdx.x;
    if (i < n) reaction[i] = reactants[i] - products[i];
}

extern "C" void kernel_launch(void* const* d_in, const int* in_sizes, int n_in,
                              void* d_out, int out_size, void* d_ws, size_t ws_size,
                              hipStream_t stream) {
    const float* x[3]   = {(const float*)d_in[0], (const float*)d_in[5],  (const float*)d_in[10]};
    const float* ein[3] = {(const float*)d_in[1], (const float*)d_in[6],  (const float*)d_in[11]};
    const int*   src[3] = {(const int*)d_in[2],   (const int*)d_in[7],    (const int*)d_in[12]};
    const int*   dst[3] = {(const int*)d_in[3],   (const int*)d_in[8],    (const int*)d_in[13]};
    const float* Wn = (const float*)d_in[15];
    const float* bn = (const float*)d_in[16];
    const float* We = (const float*)d_in[17];
    const float* be = (const float*)d_in[18];
    const float* W1 = (const float*)d_in[19];
    const float* b1 = (const float*)d_in[20];
    const float* W2 = (const float*)d_in[21];
    const float* b2 = (const float*)d_in[22];

    char* ws = (char*)d_ws;
    size_t off = 0;
    auto alloc = [&](size_t bytes) {
        char* p = ws + off; off += (bytes + 1023) & ~(size_t)1023; return p;
    };
    _Float16* h     = (_Float16*)alloc((size_t)N_NODES * HPAD * 2);   // 40 MiB
    _Float16* zbuf  = (_Float16*)alloc((size_t)N_NODES * HPAD * 2);   // 40 MiB
    _Float16* tbuf  = (_Float16*)alloc((size_t)N_NODES * HPAD * 2);   // 40 MiB
    _Float16* ehcsr = (_Float16*)alloc((size_t)N_EDGES * HPAD * 2);   // 80 MiB
    int*      counts= (int*)alloc((size_t)N_NODES * 4);               // \ contiguous
    int*      cnt   = (int*)alloc((size_t)N_NODES * 4);               // /  memset pair
    int*      part  = (int*)alloc((size_t)N_NODES * 4);
    int*      bsum  = (int*)alloc(256 * 4);
    int*      bpart = (int*)alloc(256 * 4);
    int*      bzero = (int*)alloc(4);
    int*      rowptr= (int*)alloc((size_t)(N_NODES + 1) * 4);
    int2*     se    = (int2*)alloc((size_t)N_EDGES * 8);
    _Float16* Wt1   = (_Float16*)alloc((size_t)3 * 384 * HPAD * 2);
    _Float16* Wt2   = (_Float16*)alloc((size_t)3 * 384 * HPAD * 2);
    _Float16* Wnt   = (_Float16*)alloc((size_t)384 * 64 * 2);
    _Float16* Wet   = (_Float16*)alloc((size_t)384 * 32 * 2);
    // overlays (both dead before their hosts are written):
    _Float16* xh    = (_Float16*)zbuf;   // consumed by node-proj GEMM before gather writes zbuf
    _Float16* ecsr  = (_Float16*)tbuf;   // consumed by eh-GEMM before GEMM1 writes tbuf

    if (off > ws_size) return;   // graceful diagnostic failure if ws too small

    for (int l = 0; l < 3; ++l) {
        prepack_w<<<(384 * HPAD + 255) / 256, 256, 0, stream>>>(W1 + l * 90000, Wt1 + l * 384 * HPAD, HPAD, 300);
        prepack_w<<<(384 * HPAD + 255) / 256, 256, 0, stream>>>(W2 + l * 90000, Wt2 + l * 384 * HPAD, HPAD, 300);
    }
    prepack_w<<<(384 * 64 + 255) / 256, 256, 0, stream>>>(Wn, Wnt, 64, 64);
    prepack_w<<<(384 * 32 + 255) / 256, 256, 0, stream>>>(We, Wet, 32, 16);
    hipMemsetAsync(bzero, 0, 4, stream);

    float* outp      = (float*)d_out;
    float* reaction  = outp;
    float* reactants = outp + (size_t)BB * HDIM;
    float* products  = outp + (size_t)2 * BB * HDIM;

    const int EG = (N_EDGES + 255) / 256;
    for (int g = 0; g < 3; ++g) {
        // node projection: h = relu(x @ Wn + bn)
        cvt_x<<<(N_NODES * 64 + 255) / 256, 256, 0, stream>>>(x[g], xh, N_NODES * 64);
        gemm_f16<true><<<512 * 3, 256, 0, stream>>>(xh, Wnt, bn, h, N_NODES, 64);

        // CSR build (incoming edges per node), natural node order
        hipMemsetAsync(counts, 0, (size_t)2 * N_NODES * 4, stream);   // counts + cnt
        hist_kernel<<<EG, 256, 0, stream>>>(dst[g], counts);
        scan_block<<<256, 256, 0, stream>>>(counts, part, bsum, 256);
        scan_block<<<1, 256, 0, stream>>>(bsum, bpart, bzero, 1);
        add_offsets<<<256, 256, 0, stream>>>(part, bpart, rowptr);
        scatter_csr<<<EG, 256, 0, stream>>>(src[g], dst[g], rowptr, cnt, se);

        // edge projection once per graph, in CSR order: ehcsr = ecsr @ We + be
        cvt_e_csr<<<(N_EDGES * 32 + 255) / 256, 256, 0, stream>>>(ein[g], se, ecsr);
        gemm_f16<false><<<1024 * 3, 256, 0, stream>>>(ecsr, Wet, be, ehcsr, N_EDGES, 32);

        for (int l = 0; l < 3; ++l) {
            gather_z<<<2048, 320, 0, stream>>>(h, ehcsr, se, rowptr, zbuf, 2048);
            // t = relu(z @ W1[l] + b1[l])
            gemm_f16<true><<<512 * 3, 256, 0, stream>>>(zbuf, Wt1 + l * 384 * HPAD, b1 + l * 300, tbuf, N_NODES, HPAD);
            // h = t @ W2[l] + b2[l]  (+relu if l<2)
            if (l < 2)
                gemm_f16<true ><<<512 * 3, 256, 0, stream>>>(tbuf, Wt2 + l * 384 * HPAD, b2 + l * 300, h, N_NODES, HPAD);
            else
                gemm_f16<false><<<512 * 3, 256, 0, stream>>>(tbuf, Wt2 + l * 384 * HPAD, b2 + l * 300, h, N_NODES, HPAD);
        }
        if (g == 0)      pool_kernel<<<BB, 128, 0, stream>>>(h, reactants, 0);
        else if (g == 1) pool_kernel<<<BB, 128, 0, stream>>>(h, reactants, 1);
        else             pool_kernel<<<BB, 128, 0, stream>>>(h, products, 0);
    }
    diff_kernel<<<((BB * HDIM) + 255) / 256, 256, 0, stream>>>(reaction, reactants, products, BB * HDIM);
}

// Round 14
// 1097.839 us; speedup vs baseline: 1.3713x; 1.1414x over previous
//
#include <hip/hip_runtime.h>

typedef _Float16 half8 __attribute__((ext_vector_type(8)));
typedef _Float16 half4 __attribute__((ext_vector_type(4)));
typedef float    f32x4 __attribute__((ext_vector_type(4)));

#define N_NODES 65536
#define N_EDGES 131072
#define BB      2048
#define HDIM    300
#define HPAD    320   // K padded to multiple of 32

// ---------------- prepack: dst[384][Kpad] = W[k][n]  (B^T panel, zero-padded)
__global__ __launch_bounds__(256) void prepack_w(const float* __restrict__ src,
                                                 _Float16* __restrict__ dst,
                                                 int Kpad, int Kreal) {
    int idx = blockIdx.x * 256 + threadIdx.x;
    int n = idx / Kpad, k = idx - n * Kpad;
    if (n >= 384) return;
    float v = (n < 300 && k < Kreal) ? src[k * 300 + n] : 0.f;
    dst[idx] = (_Float16)v;
}

__global__ __launch_bounds__(256) void cvt_x(const float* __restrict__ x,
                                             _Float16* __restrict__ xh, int n) {
    int i = blockIdx.x * 256 + threadIdx.x;
    if (i < n) xh[i] = (_Float16)x[i];
}

// edge feats -> f16, permuted into CSR order, zero-padded to 32 cols
__global__ __launch_bounds__(256) void cvt_e_csr(const float* __restrict__ ein,
                                                 const int2* __restrict__ se,
                                                 _Float16* __restrict__ ecsr) {
    int i = blockIdx.x * 256 + threadIdx.x;
    if (i >= N_EDGES * 32) return;
    int k = i & 31, s = i >> 5;
    int e = se[s].y;
    ecsr[i] = (_Float16)(k < 16 ? ein[(size_t)e * 16 + k] : 0.f);
}

__device__ __forceinline__ void gload16(const _Float16* g, _Float16* l) {
    __builtin_amdgcn_global_load_lds(
        (const __attribute__((address_space(1))) void*)g,
        (__attribute__((address_space(3))) void*)l, 16, 0, 0);
}

// ---------------- MFMA GEMM: out[M][320] = op( A[M][K] @ Bp^T ) + bias
// Bp is [384][K] f16. 128x128 tile, 4 waves, 64x64/wave.
// global_load_lds staging, 3-buf, single barrier/iter, counted vmcnt,
// XOR-swizzled LDS, XCD-grouped blocks, LDS-transposed coalesced epilogue.
// (r13's deadwave trim removed: in-loop branch defeated compiler scheduling,
//  cost ~7us/dispatch across ALL blocks — measured r9 vs r13.)
template <bool RELU>
__global__ __launch_bounds__(256) void gemm_f16(
        const _Float16* __restrict__ A,
        const _Float16* __restrict__ Bp, const float* __restrict__ bias,
        _Float16* __restrict__ out, int M, int K) {
    __shared__ _Float16 lds[3][2][128 * 32];   // [buf][A/B][row*32+k] : 48 KB

    // XCD grouping: the 3 nt-siblings of one mt land on the same XCD (bid%8)
    int bid = blockIdx.x;
    int xcd = bid & 7, grp = bid >> 3;
    int mt = xcd + 8 * (grp / 3);
    int nt = grp % 3;
    int m0 = mt * 128, n0 = nt * 128;
    int t = threadIdx.x;
    int lane = t & 63, w = t >> 6;
    int wr = w >> 1, wc = w & 1;

    int srow[2], sko[2];
    #pragma unroll
    for (int q = 0; q < 2; ++q) {
        int row = (w * 2 + q) * 16 + (lane >> 2);
        int ch = (lane & 3) ^ ((row >> 1) & 3);
        srow[q] = row; sko[q] = ch * 8;
    }

    f32x4 acc[4][4] = {};
    int NK = K >> 5;

    auto stage = [&](int buf, int k0) {
        #pragma unroll
        for (int q = 0; q < 2; ++q) {
            gload16(&A[(size_t)(m0 + srow[q]) * K + k0 + sko[q]], &lds[buf][0][(w * 2 + q) * 512]);
            gload16(&Bp[(size_t)(n0 + srow[q]) * K + k0 + sko[q]], &lds[buf][1][(w * 2 + q) * 512]);
        }
    };

    stage(0, 0);
    if (NK > 1) stage(1, 32);
    for (int kt = 0; kt < NK; ++kt) {
        int cur = kt % 3;
        if (kt + 1 < NK) {
            asm volatile("s_waitcnt vmcnt(4)" ::: "memory");   // stage kt landed
        } else {
            asm volatile("s_waitcnt vmcnt(0)" ::: "memory");
        }
        __builtin_amdgcn_s_barrier();
        __builtin_amdgcn_sched_barrier(0);
        if (kt + 2 < NK) stage((kt + 2) % 3, (kt + 2) << 5);

        int lr = lane & 15, hi = lane >> 4;
        half8 af[4], bf[4];
        #pragma unroll
        for (int i = 0; i < 4; ++i) {
            int row = wr * 64 + i * 16 + lr;
            int lk = (hi ^ ((row >> 1) & 3)) * 8;
            af[i] = *(const half8*)&lds[cur][0][row * 32 + lk];
        }
        #pragma unroll
        for (int j = 0; j < 4; ++j) {
            int row = wc * 64 + j * 16 + lr;
            int lk = (hi ^ ((row >> 1) & 3)) * 8;
            bf[j] = *(const half8*)&lds[cur][1][row * 32 + lk];
        }
        #pragma unroll
        for (int i = 0; i < 4; ++i)
            #pragma unroll
            for (int j = 0; j < 4; ++j)
                acc[i][j] = __builtin_amdgcn_mfma_f32_16x16x32_f16(af[i], bf[j], acc[i][j], 0, 0, 0);
    }
    __syncthreads();   // protect lds reuse by epilogue

    // epilogue: acc -> LDS (f16, 128x128) -> coalesced 256B stores
    _Float16* ct = &lds[0][0][0];
    {
        int lr = lane & 15, lq = (lane >> 4) * 4;
        #pragma unroll
        for (int j = 0; j < 4; ++j) {
            int col = wc * 64 + j * 16 + lr;
            int gcol = n0 + col;
            float bv = (gcol < 300) ? bias[gcol] : 0.f;
            #pragma unroll
            for (int i = 0; i < 4; ++i) {
                int rbase = wr * 64 + i * 16 + lq;
                #pragma unroll
                for (int q = 0; q < 4; ++q) {
                    float v = acc[i][j][q] + bv;
                    if (RELU) v = v > 0.f ? v : 0.f;
                    if (gcol >= 300) v = 0.f;
                    ct[(rbase + q) * 128 + col] = (_Float16)v;
                }
            }
        }
    }
    __syncthreads();
    #pragma unroll
    for (int r = 0; r < 8; ++r) {
        int row = r * 16 + (t >> 4);
        int c8 = (t & 15) * 8;
        if (n0 + c8 < HPAD) {
            half8 v = *(const half8*)&ct[row * 128 + c8];
            *(half8*)&out[(size_t)(m0 + row) * HPAD + n0 + c8] = v;
        }
    }
}

// ---------------- CSR build (natural node order) ----------------
__global__ __launch_bounds__(256) void hist_kernel(const int* __restrict__ dst,
                                                   int* __restrict__ counts) {
    int e = blockIdx.x * 256 + threadIdx.x;
    if (e < N_EDGES) atomicAdd(&counts[dst[e]], 1);
}

__global__ __launch_bounds__(256) void scan_block(const int* __restrict__ in,
                                                  int* __restrict__ partial,
                                                  int* __restrict__ bsum, int nb) {
    __shared__ int s[256];
    int b = blockIdx.x, t = threadIdx.x;
    int v = (b < nb) ? in[b * 256 + t] : 0;
    s[t] = v;
    __syncthreads();
    for (int o = 1; o < 256; o <<= 1) {
        int x = (t >= o) ? s[t - o] : 0;
        __syncthreads();
        s[t] += x;
        __syncthreads();
    }
    partial[b * 256 + t] = s[t] - v;      // exclusive
    if (t == 255 && bsum) bsum[b] = s[255];
}

__global__ __launch_bounds__(256) void add_offsets(const int* __restrict__ partial,
                                                   const int* __restrict__ boff,
                                                   int* __restrict__ rowptr) {
    int i = blockIdx.x * 256 + threadIdx.x;
    if (i < N_NODES) rowptr[i] = partial[i] + boff[i >> 8];
    if (i == 0) rowptr[N_NODES] = N_EDGES;
}

__global__ __launch_bounds__(256) void scatter_csr(const int* __restrict__ src,
                                                   const int* __restrict__ dst,
                                                   const int* __restrict__ rowptr,
                                                   int* __restrict__ cnt,
                                                   int2* __restrict__ se) {
    int e = blockIdx.x * 256 + threadIdx.x;
    if (e >= N_EDGES) return;
    int d = dst[e];
    int pos = atomicAdd(&cnt[d], 1);
    se[rowptr[d] + pos] = make_int2(src[e], e);
}

// ---------------- gather: z[d] = h[d] + sum_{s in row(d)} relu(h[src_s] + ehcsr[s])
// ehcsr in CSR order -> sequential streaming. 320 thr = 8 node-slots x 40 half8.
__global__ __launch_bounds__(320) void gather_z(
        const _Float16* __restrict__ h, const _Float16* __restrict__ ehcsr,
        const int2* __restrict__ se, const int* __restrict__ rowptr,
        _Float16* __restrict__ z, int nblocks) {
    int t = threadIdx.x;
    int c = t % 40, ns = t / 40;
    for (int node = blockIdx.x * 8 + ns; node < N_NODES; node += nblocks * 8) {
        int r0 = rowptr[node], r1 = rowptr[node + 1];
        half8 hn = *(const half8*)&h[(size_t)node * HPAD + c * 8];
        half8 acc = {};
        for (int s = r0; s < r1; s += 4) {
            int nb = r1 - s;
            int idx[4];
            idx[0] = s;
            idx[1] = s + (1 < nb ? 1 : 0);
            idx[2] = s + (2 < nb ? 2 : 0);
            idx[3] = s + (3 < nb ? 3 : 0);
            half8 hv[4], ev[4];
            #pragma unroll
            for (int u = 0; u < 4; ++u) {
                int sp = se[idx[u]].x;
                hv[u] = *(const half8*)&h[(size_t)sp * HPAD + c * 8];
                ev[u] = *(const half8*)&ehcsr[(size_t)idx[u] * HPAD + c * 8];
            }
            #pragma unroll
            for (int u = 0; u < 4; ++u) {
                half8 m = hv[u] + ev[u];
                #pragma unroll
                for (int j = 0; j < 8; ++j)
                    m[j] = m[j] > (_Float16)0 ? m[j] : (_Float16)0;
                if (u < nb) acc += m;
            }
        }
        half8 o = hn + acc;          // pad cols: 0 + 0 = 0
        *(half8*)&z[(size_t)node * HPAD + c * 8] = o;
    }
}

// ---------------- per-molecule sum pool (32 consecutive rows)
__global__ __launch_bounds__(128) void pool_kernel(const _Float16* __restrict__ h,
                                                   float* __restrict__ out, int add) {
    int b = blockIdx.x, t = threadIdx.x;
    if (t >= 75) return;
    float a0 = 0, a1 = 0, a2 = 0, a3 = 0;
    for (int r = 0; r < 32; ++r) {
        half4 v = *(const half4*)&h[(size_t)(b * 32 + r) * HPAD + t * 4];
        a0 += (float)v[0]; a1 += (float)v[1]; a2 += (float)v[2]; a3 += (float)v[3];
    }
    f32x4 o = {a0, a1, a2, a3};
    if (add) o += *(f32x4*)&out[b * 300 + t * 4];
    *(f32x4*)&out[b * 300 + t * 4] = o;
}

__global__ __launch_bounds__(256) void diff_kernel(float* __restrict__ reaction,
                                                   const float* __restrict__ reactants,
                                                   const float* __restrict__ products, int n) {
    int i = blockIdx.x * 256 + threadIdx.x;
    if (i < n) reaction[i] = reactants[i] - products[i];
}

extern "C" void kernel_launch(void* const* d_in, const int* in_sizes, int n_in,
                              void* d_out, int out_size, void* d_ws, size_t ws_size,
                              hipStream_t stream) {
    const float* x[3]   = {(const float*)d_in[0], (const float*)d_in[5],  (const float*)d_in[10]};
    const float* ein[3] = {(const float*)d_in[1], (const float*)d_in[6],  (const float*)d_in[11]};
    const int*   src[3] = {(const int*)d_in[2],   (const int*)d_in[7],    (const int*)d_in[12]};
    const int*   dst[3] = {(const int*)d_in[3],   (const int*)d_in[8],    (const int*)d_in[13]};
    const float* Wn = (const float*)d_in[15];
    const float* bn = (const float*)d_in[16];
    const float* We = (const float*)d_in[17];
    const float* be = (const float*)d_in[18];
    const float* W1 = (const float*)d_in[19];
    const float* b1 = (const float*)d_in[20];
    const float* W2 = (const float*)d_in[21];
    const float* b2 = (const float*)d_in[22];

    char* ws = (char*)d_ws;
    size_t off = 0;
    auto alloc = [&](size_t bytes) {
        char* p = ws + off; off += (bytes + 1023) & ~(size_t)1023; return p;
    };
    _Float16* h     = (_Float16*)alloc((size_t)N_NODES * HPAD * 2);   // 40 MiB
    _Float16* zbuf  = (_Float16*)alloc((size_t)N_NODES * HPAD * 2);   // 40 MiB
    _Float16* tbuf  = (_Float16*)alloc((size_t)N_NODES * HPAD * 2);   // 40 MiB
    _Float16* ehcsr = (_Float16*)alloc((size_t)N_EDGES * HPAD * 2);   // 80 MiB
    int*      counts= (int*)alloc((size_t)N_NODES * 4);               // \ contiguous
    int*      cnt   = (int*)alloc((size_t)N_NODES * 4);               // /  memset pair
    int*      part  = (int*)alloc((size_t)N_NODES * 4);
    int*      bsum  = (int*)alloc(256 * 4);
    int*      bpart = (int*)alloc(256 * 4);
    int*      bzero = (int*)alloc(4);
    int*      rowptr= (int*)alloc((size_t)(N_NODES + 1) * 4);
    int2*     se    = (int2*)alloc((size_t)N_EDGES * 8);
    _Float16* Wt1   = (_Float16*)alloc((size_t)3 * 384 * HPAD * 2);
    _Float16* Wt2   = (_Float16*)alloc((size_t)3 * 384 * HPAD * 2);
    _Float16* Wnt   = (_Float16*)alloc((size_t)384 * 64 * 2);
    _Float16* Wet   = (_Float16*)alloc((size_t)384 * 32 * 2);
    // overlays (both dead before their hosts are written):
    _Float16* xh    = (_Float16*)zbuf;   // consumed by node-proj GEMM before gather writes zbuf
    _Float16* ecsr  = (_Float16*)tbuf;   // consumed by eh-GEMM before GEMM1 writes tbuf

    if (off > ws_size) return;   // graceful diagnostic failure if ws too small

    for (int l = 0; l < 3; ++l) {
        prepack_w<<<(384 * HPAD + 255) / 256, 256, 0, stream>>>(W1 + l * 90000, Wt1 + l * 384 * HPAD, HPAD, 300);
        prepack_w<<<(384 * HPAD + 255) / 256, 256, 0, stream>>>(W2 + l * 90000, Wt2 + l * 384 * HPAD, HPAD, 300);
    }
    prepack_w<<<(384 * 64 + 255) / 256, 256, 0, stream>>>(Wn, Wnt, 64, 64);
    prepack_w<<<(384 * 32 + 255) / 256, 256, 0, stream>>>(We, Wet, 32, 16);
    hipMemsetAsync(bzero, 0, 4, stream);

    float* outp      = (float*)d_out;
    float* reaction  = outp;
    float* reactants = outp + (size_t)BB * HDIM;
    float* products  = outp + (size_t)2 * BB * HDIM;

    const int EG = (N_EDGES + 255) / 256;
    for (int g = 0; g < 3; ++g) {
        // node projection: h = relu(x @ Wn + bn)
        cvt_x<<<(N_NODES * 64 + 255) / 256, 256, 0, stream>>>(x[g], xh, N_NODES * 64);
        gemm_f16<true><<<512 * 3, 256, 0, stream>>>(xh, Wnt, bn, h, N_NODES, 64);

        // CSR build (incoming edges per node), natural node order
        hipMemsetAsync(counts, 0, (size_t)2 * N_NODES * 4, stream);   // counts + cnt
        hist_kernel<<<EG, 256, 0, stream>>>(dst[g], counts);
        scan_block<<<256, 256, 0, stream>>>(counts, part, bsum, 256);
        scan_block<<<1, 256, 0, stream>>>(bsum, bpart, bzero, 1);
        add_offsets<<<256, 256, 0, stream>>>(part, bpart, rowptr);
        scatter_csr<<<EG, 256, 0, stream>>>(src[g], dst[g], rowptr, cnt, se);

        // edge projection once per graph, in CSR order: ehcsr = ecsr @ We + be
        cvt_e_csr<<<(N_EDGES * 32 + 255) / 256, 256, 0, stream>>>(ein[g], se, ecsr);
        gemm_f16<false><<<1024 * 3, 256, 0, stream>>>(ecsr, Wet, be, ehcsr, N_EDGES, 32);

        for (int l = 0; l < 3; ++l) {
            gather_z<<<2048, 320, 0, stream>>>(h, ehcsr, se, rowptr, zbuf, 2048);
            // t = relu(z @ W1[l] + b1[l])
            gemm_f16<true><<<512 * 3, 256, 0, stream>>>(zbuf, Wt1 + l * 384 * HPAD, b1 + l * 300, tbuf, N_NODES, HPAD);
            // h = t @ W2[l] + b2[l]  (+relu if l<2)
            if (l < 2)
                gemm_f16<true ><<<512 * 3, 256, 0, stream>>>(tbuf, Wt2 + l * 384 * HPAD, b2 + l * 300, h, N_NODES, HPAD);
            else
                gemm_f16<false><<<512 * 3, 256, 0, stream>>>(tbuf, Wt2 + l * 384 * HPAD, b2 + l * 300, h, N_NODES, HPAD);
        }
        if (g == 0)      pool_kernel<<<BB, 128, 0, stream>>>(h, reactants, 0);
        else if (g == 1) pool_kernel<<<BB, 128, 0, stream>>>(h, reactants, 1);
        else             pool_kernel<<<BB, 128, 0, stream>>>(h, products, 0);
    }
    diff_kernel<<<((BB * HDIM) + 255) / 256, 256, 0, stream>>>(reaction, reactants, products, BB * HDIM);
}

// Round 15
// 1043.195 us; speedup vs baseline: 1.4431x; 1.0524x over previous
//
#include <hip/hip_runtime.h>

typedef _Float16 half8 __attribute__((ext_vector_type(8)));
typedef _Float16 half4 __attribute__((ext_vector_type(4)));
typedef float    f32x4 __attribute__((ext_vector_type(4)));

#define N_NODES 65536
#define N_EDGES 131072
#define BB      2048
#define HDIM    300
#define HPAD    320   // K padded to multiple of 32

// ---------------- prepack: dst[384][Kpad] = W[k][n]  (B^T panel, zero-padded)
__global__ __launch_bounds__(256) void prepack_w(const float* __restrict__ src,
                                                 _Float16* __restrict__ dst,
                                                 int Kpad, int Kreal) {
    int idx = blockIdx.x * 256 + threadIdx.x;
    int n = idx / Kpad, k = idx - n * Kpad;
    if (n >= 384) return;
    float v = (n < 300 && k < Kreal) ? src[k * 300 + n] : 0.f;
    dst[idx] = (_Float16)v;
}

__global__ __launch_bounds__(256) void cvt_x(const float* __restrict__ x,
                                             _Float16* __restrict__ xh, int n) {
    int i = blockIdx.x * 256 + threadIdx.x;
    if (i < n) xh[i] = (_Float16)x[i];
}

// edge feats -> f16, permuted into CSR order, zero-padded to 32 cols
__global__ __launch_bounds__(256) void cvt_e_csr(const float* __restrict__ ein,
                                                 const int2* __restrict__ se,
                                                 _Float16* __restrict__ ecsr) {
    int i = blockIdx.x * 256 + threadIdx.x;
    if (i >= N_EDGES * 32) return;
    int k = i & 31, s = i >> 5;
    int e = se[s].y;
    ecsr[i] = (_Float16)(k < 16 ? ein[(size_t)e * 16 + k] : 0.f);
}

__device__ __forceinline__ void gload16(const _Float16* g, _Float16* l) {
    __builtin_amdgcn_global_load_lds(
        (const __attribute__((address_space(1))) void*)g,
        (__attribute__((address_space(3))) void*)l, 16, 0, 0);
}

// ---------------- MFMA GEMM: out[M][320] = op( A[M][K] @ Bp^T ) + bias
// 2x160 N-tiling (no dead columns): block = 128x160, 4 waves of 64x80,
// acc[4][5]=80 f32. A staged 128 rows + B staged 192 rows (2+3 gload16/thr),
// 2-buffer, 2 barriers/iter (r6-verified), counted vmcnt(5), XOR swizzle.
// Epilogue ct (128x160 f16 = 40KB) exactly overlays the two staging buffers.
template <bool RELU>
__global__ __launch_bounds__(256, 3) void gemm_f16(
        const _Float16* __restrict__ A,
        const _Float16* __restrict__ Bp, const float* __restrict__ bias,
        _Float16* __restrict__ out, int M, int K) {
    __shared__ _Float16 lds[2][10240];   // [buf][A 128*32 | B 192*32] = 40 KB

    // XCD grouping: both nt-siblings of one mt land on the same XCD (bid%8)
    int bid = blockIdx.x;
    int xcd = bid & 7, grp = bid >> 3;
    int mt = xcd + 8 * (grp >> 1);
    int nt = grp & 1;
    int m0 = mt * 128, n0 = nt * 160;
    int t = threadIdx.x;
    int lane = t & 63, w = t >> 6;
    int wr = w >> 1, wcn = (w & 1) * 80;   // wave M-half (64 rows), N-base (80)

    f32x4 acc[4][5] = {};
    int NK = K >> 5;

    auto stage = [&](int buf, int k0) {
        #pragma unroll
        for (int q = 0; q < 2; ++q) {           // A: 512 slots (128 rows x 4)
            int slot = q * 256 + t;
            int row = slot >> 2;
            int ch = ((slot & 3) ^ ((row >> 1) & 3)) << 3;
            gload16(&A[(size_t)(m0 + row) * K + k0 + ch],
                    &lds[buf][(q * 256 + w * 64) * 8]);
        }
        #pragma unroll
        for (int q = 0; q < 3; ++q) {           // B: 768 slots (192 rows x 4)
            int slot = q * 256 + t;
            int row = slot >> 2;
            int ch = ((slot & 3) ^ ((row >> 1) & 3)) << 3;
            gload16(&Bp[(size_t)(n0 + row) * K + k0 + ch],
                    &lds[buf][4096 + (q * 256 + w * 64) * 8]);
        }
    };

    stage(0, 0);
    for (int kt = 0; kt < NK; ++kt) {
        int cur = kt & 1;
        if (kt + 1 < NK) {
            stage(cur ^ 1, (kt + 1) << 5);
            asm volatile("s_waitcnt vmcnt(5)" ::: "memory");   // stage kt landed, kt+1 in flight
        } else {
            asm volatile("s_waitcnt vmcnt(0)" ::: "memory");
        }
        __builtin_amdgcn_s_barrier();
        __builtin_amdgcn_sched_barrier(0);

        int lr = lane & 15, hi = lane >> 4;
        half8 af[4], bf[5];
        #pragma unroll
        for (int i = 0; i < 4; ++i) {
            int row = wr * 64 + i * 16 + lr;
            int lk = (hi ^ ((row >> 1) & 3)) * 8;
            af[i] = *(const half8*)&lds[cur][row * 32 + lk];
        }
        #pragma unroll
        for (int j = 0; j < 5; ++j) {
            int row = wcn + j * 16 + lr;
            int lk = (hi ^ ((row >> 1) & 3)) * 8;
            bf[j] = *(const half8*)&lds[cur][4096 + row * 32 + lk];
        }
        #pragma unroll
        for (int i = 0; i < 4; ++i)
            #pragma unroll
            for (int j = 0; j < 5; ++j)
                acc[i][j] = __builtin_amdgcn_mfma_f32_16x16x32_f16(af[i], bf[j], acc[i][j], 0, 0, 0);

        __builtin_amdgcn_sched_barrier(0);
        __builtin_amdgcn_s_barrier();   // all reads of cur done before it is restaged
    }
    __syncthreads();

    // epilogue: acc -> ct (128x160 f16, overlays both bufs) -> coalesced stores
    _Float16* ct = &lds[0][0];
    {
        int lr = lane & 15, lq = (lane >> 4) * 4;
        #pragma unroll
        for (int j = 0; j < 5; ++j) {
            int col = wcn + j * 16 + lr;
            int gcol = n0 + col;
            float bv = (gcol < 300) ? bias[gcol] : 0.f;
            #pragma unroll
            for (int i = 0; i < 4; ++i) {
                int rbase = wr * 64 + i * 16 + lq;
                #pragma unroll
                for (int q = 0; q < 4; ++q) {
                    float v = acc[i][j][q] + bv;
                    if (RELU) v = v > 0.f ? v : 0.f;
                    if (gcol >= 300) v = 0.f;
                    ct[(rbase + q) * 160 + col] = (_Float16)v;
                }
            }
        }
    }
    __syncthreads();
    #pragma unroll
    for (int r = 0; r < 10; ++r) {
        int idx = r * 256 + t;
        int row = idx / 20, c = idx - row * 20;
        half8 v = *(const half8*)&ct[row * 160 + c * 8];
        *(half8*)&out[(size_t)(m0 + row) * HPAD + n0 + c * 8] = v;
    }
}

// ---------------- CSR build (natural node order) ----------------
__global__ __launch_bounds__(256) void hist_kernel(const int* __restrict__ dst,
                                                   int* __restrict__ counts) {
    int e = blockIdx.x * 256 + threadIdx.x;
    if (e < N_EDGES) atomicAdd(&counts[dst[e]], 1);
}

__global__ __launch_bounds__(256) void scan_block(const int* __restrict__ in,
                                                  int* __restrict__ partial,
                                                  int* __restrict__ bsum, int nb) {
    __shared__ int s[256];
    int b = blockIdx.x, t = threadIdx.x;
    int v = (b < nb) ? in[b * 256 + t] : 0;
    s[t] = v;
    __syncthreads();
    for (int o = 1; o < 256; o <<= 1) {
        int x = (t >= o) ? s[t - o] : 0;
        __syncthreads();
        s[t] += x;
        __syncthreads();
    }
    partial[b * 256 + t] = s[t] - v;      // exclusive
    if (t == 255 && bsum) bsum[b] = s[255];
}

__global__ __launch_bounds__(256) void add_offsets(const int* __restrict__ partial,
                                                   const int* __restrict__ boff,
                                                   int* __restrict__ rowptr) {
    int i = blockIdx.x * 256 + threadIdx.x;
    if (i < N_NODES) rowptr[i] = partial[i] + boff[i >> 8];
    if (i == 0) rowptr[N_NODES] = N_EDGES;
}

__global__ __launch_bounds__(256) void scatter_csr(const int* __restrict__ src,
                                                   const int* __restrict__ dst,
                                                   const int* __restrict__ rowptr,
                                                   int* __restrict__ cnt,
                                                   int2* __restrict__ se) {
    int e = blockIdx.x * 256 + threadIdx.x;
    if (e >= N_EDGES) return;
    int d = dst[e];
    int pos = atomicAdd(&cnt[d], 1);
    se[rowptr[d] + pos] = make_int2(src[e], e);
}

// ---------------- gather: z[d] = h[d] + sum_{s in row(d)} relu(h[src_s] + ehcsr[s])
// ehcsr in CSR order -> sequential streaming. 320 thr = 8 node-slots x 40 half8.
__global__ __launch_bounds__(320) void gather_z(
        const _Float16* __restrict__ h, const _Float16* __restrict__ ehcsr,
        const int2* __restrict__ se, const int* __restrict__ rowptr,
        _Float16* __restrict__ z, int nblocks) {
    int t = threadIdx.x;
    int c = t % 40, ns = t / 40;
    for (int node = blockIdx.x * 8 + ns; node < N_NODES; node += nblocks * 8) {
        int r0 = rowptr[node], r1 = rowptr[node + 1];
        half8 hn = *(const half8*)&h[(size_t)node * HPAD + c * 8];
        half8 acc = {};
        for (int s = r0; s < r1; s += 4) {
            int nb = r1 - s;
            int idx[4];
            idx[0] = s;
            idx[1] = s + (1 < nb ? 1 : 0);
            idx[2] = s + (2 < nb ? 2 : 0);
            idx[3] = s + (3 < nb ? 3 : 0);
            half8 hv[4], ev[4];
            #pragma unroll
            for (int u = 0; u < 4; ++u) {
                int sp = se[idx[u]].x;
                hv[u] = *(const half8*)&h[(size_t)sp * HPAD + c * 8];
                ev[u] = *(const half8*)&ehcsr[(size_t)idx[u] * HPAD + c * 8];
            }
            #pragma unroll
            for (int u = 0; u < 4; ++u) {
                half8 m = hv[u] + ev[u];
                #pragma unroll
                for (int j = 0; j < 8; ++j)
                    m[j] = m[j] > (_Float16)0 ? m[j] : (_Float16)0;
                if (u < nb) acc += m;
            }
        }
        half8 o = hn + acc;          // pad cols: 0 + 0 = 0
        *(half8*)&z[(size_t)node * HPAD + c * 8] = o;
    }
}

// ---------------- per-molecule sum pool (32 consecutive rows)
__global__ __launch_bounds__(128) void pool_kernel(const _Float16* __restrict__ h,
                                                   float* __restrict__ out, int add) {
    int b = blockIdx.x, t = threadIdx.x;
    if (t >= 75) return;
    float a0 = 0, a1 = 0, a2 = 0, a3 = 0;
    for (int r = 0; r < 32; ++r) {
        half4 v = *(const half4*)&h[(size_t)(b * 32 + r) * HPAD + t * 4];
        a0 += (float)v[0]; a1 += (float)v[1]; a2 += (float)v[2]; a3 += (float)v[3];
    }
    f32x4 o = {a0, a1, a2, a3};
    if (add) o += *(f32x4*)&out[b * 300 + t * 4];
    *(f32x4*)&out[b * 300 + t * 4] = o;
}

__global__ __launch_bounds__(256) void diff_kernel(float* __restrict__ reaction,
                                                   const float* __restrict__ reactants,
                                                   const float* __restrict__ products, int n) {
    int i = blockIdx.x * 256 + threadIdx.x;
    if (i < n) reaction[i] = reactants[i] - products[i];
}

extern "C" void kernel_launch(void* const* d_in, const int* in_sizes, int n_in,
                              void* d_out, int out_size, void* d_ws, size_t ws_size,
                              hipStream_t stream) {
    const float* x[3]   = {(const float*)d_in[0], (const float*)d_in[5],  (const float*)d_in[10]};
    const float* ein[3] = {(const float*)d_in[1], (const float*)d_in[6],  (const float*)d_in[11]};
    const int*   src[3] = {(const int*)d_in[2],   (const int*)d_in[7],    (const int*)d_in[12]};
    const int*   dst[3] = {(const int*)d_in[3],   (const int*)d_in[8],    (const int*)d_in[13]};
    const float* Wn = (const float*)d_in[15];
    const float* bn = (const float*)d_in[16];
    const float* We = (const float*)d_in[17];
    const float* be = (const float*)d_in[18];
    const float* W1 = (const float*)d_in[19];
    const float* b1 = (const float*)d_in[20];
    const float* W2 = (const float*)d_in[21];
    const float* b2 = (const float*)d_in[22];

    char* ws = (char*)d_ws;
    size_t off = 0;
    auto alloc = [&](size_t bytes) {
        char* p = ws + off; off += (bytes + 1023) & ~(size_t)1023; return p;
    };
    _Float16* h     = (_Float16*)alloc((size_t)N_NODES * HPAD * 2);   // 40 MiB
    _Float16* zbuf  = (_Float16*)alloc((size_t)N_NODES * HPAD * 2);   // 40 MiB
    _Float16* tbuf  = (_Float16*)alloc((size_t)N_NODES * HPAD * 2);   // 40 MiB
    _Float16* ehcsr = (_Float16*)alloc((size_t)N_EDGES * HPAD * 2);   // 80 MiB
    int*      counts= (int*)alloc((size_t)N_NODES * 4);               // \ contiguous
    int*      cnt   = (int*)alloc((size_t)N_NODES * 4);               // /  memset pair
    int*      part  = (int*)alloc((size_t)N_NODES * 4);
    int*      bsum  = (int*)alloc(256 * 4);
    int*      bpart = (int*)alloc(256 * 4);
    int*      bzero = (int*)alloc(4);
    int*      rowptr= (int*)alloc((size_t)(N_NODES + 1) * 4);
    int2*     se    = (int2*)alloc((size_t)N_EDGES * 8);
    _Float16* Wt1   = (_Float16*)alloc((size_t)3 * 384 * HPAD * 2);
    _Float16* Wt2   = (_Float16*)alloc((size_t)3 * 384 * HPAD * 2);
    _Float16* Wnt   = (_Float16*)alloc((size_t)384 * 64 * 2);
    _Float16* Wet   = (_Float16*)alloc((size_t)384 * 32 * 2);
    // overlays (both dead before their hosts are written):
    _Float16* xh    = (_Float16*)zbuf;   // consumed by node-proj GEMM before gather writes zbuf
    _Float16* ecsr  = (_Float16*)tbuf;   // consumed by eh-GEMM before GEMM1 writes tbuf

    if (off > ws_size) return;   // graceful diagnostic failure if ws too small

    for (int l = 0; l < 3; ++l) {
        prepack_w<<<(384 * HPAD + 255) / 256, 256, 0, stream>>>(W1 + l * 90000, Wt1 + l * 384 * HPAD, HPAD, 300);
        prepack_w<<<(384 * HPAD + 255) / 256, 256, 0, stream>>>(W2 + l * 90000, Wt2 + l * 384 * HPAD, HPAD, 300);
    }
    prepack_w<<<(384 * 64 + 255) / 256, 256, 0, stream>>>(Wn, Wnt, 64, 64);
    prepack_w<<<(384 * 32 + 255) / 256, 256, 0, stream>>>(We, Wet, 32, 16);
    hipMemsetAsync(bzero, 0, 4, stream);

    float* outp      = (float*)d_out;
    float* reaction  = outp;
    float* reactants = outp + (size_t)BB * HDIM;
    float* products  = outp + (size_t)2 * BB * HDIM;

    const int EG = (N_EDGES + 255) / 256;
    for (int g = 0; g < 3; ++g) {
        // node projection: h = relu(x @ Wn + bn)
        cvt_x<<<(N_NODES * 64 + 255) / 256, 256, 0, stream>>>(x[g], xh, N_NODES * 64);
        gemm_f16<true><<<512 * 2, 256, 0, stream>>>(xh, Wnt, bn, h, N_NODES, 64);

        // CSR build (incoming edges per node), natural node order
        hipMemsetAsync(counts, 0, (size_t)2 * N_NODES * 4, stream);   // counts + cnt
        hist_kernel<<<EG, 256, 0, stream>>>(dst[g], counts);
        scan_block<<<256, 256, 0, stream>>>(counts, part, bsum, 256);
        scan_block<<<1, 256, 0, stream>>>(bsum, bpart, bzero, 1);
        add_offsets<<<256, 256, 0, stream>>>(part, bpart, rowptr);
        scatter_csr<<<EG, 256, 0, stream>>>(src[g], dst[g], rowptr, cnt, se);

        // edge projection once per graph, in CSR order: ehcsr = ecsr @ We + be
        cvt_e_csr<<<(N_EDGES * 32 + 255) / 256, 256, 0, stream>>>(ein[g], se, ecsr);
        gemm_f16<false><<<1024 * 2, 256, 0, stream>>>(ecsr, Wet, be, ehcsr, N_EDGES, 32);

        for (int l = 0; l < 3; ++l) {
            gather_z<<<2048, 320, 0, stream>>>(h, ehcsr, se, rowptr, zbuf, 2048);
            // t = relu(z @ W1[l] + b1[l])
            gemm_f16<true><<<512 * 2, 256, 0, stream>>>(zbuf, Wt1 + l * 384 * HPAD, b1 + l * 300, tbuf, N_NODES, HPAD);
            // h = t @ W2[l] + b2[l]  (+relu if l<2)
            if (l < 2)
                gemm_f16<true ><<<512 * 2, 256, 0, stream>>>(tbuf, Wt2 + l * 384 * HPAD, b2 + l * 300, h, N_NODES, HPAD);
            else
                gemm_f16<false><<<512 * 2, 256, 0, stream>>>(tbuf, Wt2 + l * 384 * HPAD, b2 + l * 300, h, N_NODES, HPAD);
        }
        if (g == 0)      pool_kernel<<<BB, 128, 0, stream>>>(h, reactants, 0);
        else if (g == 1) pool_kernel<<<BB, 128, 0, stream>>>(h, reactants, 1);
        else             pool_kernel<<<BB, 128, 0, stream>>>(h, products, 0);
    }
    diff_kernel<<<((BB * HDIM) + 255) / 256, 256, 0, stream>>>(reaction, reactants, products, BB * HDIM);
}

// Round 17
// 981.404 us; speedup vs baseline: 1.5340x; 1.0630x over previous
//
#include <hip/hip_runtime.h>

typedef _Float16 half8 __attribute__((ext_vector_type(8)));
typedef _Float16 half4 __attribute__((ext_vector_type(4)));
typedef __fp16   fp16x2 __attribute__((ext_vector_type(2)));
typedef float    f32x4 __attribute__((ext_vector_type(4)));
typedef float    f32x2 __attribute__((ext_vector_type(2)));

#define N_NODES 65536
#define N_EDGES 131072
#define BB      2048
#define HDIM    300
#define HPAD    320   // K padded to multiple of 32

// ---------------- prepack: dst[384][Kpad] = W[k][n]  (B^T panel, zero-padded)
__global__ __launch_bounds__(256) void prepack_w(const float* __restrict__ src,
                                                 _Float16* __restrict__ dst,
                                                 int Kpad, int Kreal) {
    int idx = blockIdx.x * 256 + threadIdx.x;
    int n = idx / Kpad, k = idx - n * Kpad;
    if (n >= 384) return;
    float v = (n < 300 && k < Kreal) ? src[k * 300 + n] : 0.f;
    dst[idx] = (_Float16)v;
}

__global__ __launch_bounds__(256) void cvt_x(const float* __restrict__ x,
                                             _Float16* __restrict__ xh, int n) {
    int i = blockIdx.x * 256 + threadIdx.x;
    if (i < n) xh[i] = (_Float16)x[i];
}

// edge feats -> f16, permuted into CSR order, zero-padded to 32 cols
__global__ __launch_bounds__(256) void cvt_e_csr(const float* __restrict__ ein,
                                                 const int2* __restrict__ se,
                                                 _Float16* __restrict__ ecsr) {
    int i = blockIdx.x * 256 + threadIdx.x;
    if (i >= N_EDGES * 32) return;
    int k = i & 31, s = i >> 5;
    int e = se[s].y;
    ecsr[i] = (_Float16)(k < 16 ? ein[(size_t)e * 16 + k] : 0.f);
}

__device__ __forceinline__ void gload16(const _Float16* g, _Float16* l) {
    __builtin_amdgcn_global_load_lds(
        (const __attribute__((address_space(1))) void*)g,
        (__attribute__((address_space(3))) void*)l, 16, 0, 0);
}

// ---------------- MFMA GEMM: out[M][320] = op( A[M][K] @ Bp^T ) + bias
// 2x160 N-tiling, block = 128x160, 4 waves of 64x80, acc[4][5]=80 f32.
// A staged 128 rows + B staged 192 rows, 2-buffer, counted vmcnt(5), XOR swizzle.
// OUT8: epilogue emits OCP fp8-e4m3 (1 byte/elem) instead of f16 — used for
// the edge-projection (eh) so gather's dominant stream is halved.
template <bool RELU, bool OUT8>
__global__ __launch_bounds__(256, 3) void gemm_f16(
        const _Float16* __restrict__ A,
        const _Float16* __restrict__ Bp, const float* __restrict__ bias,
        _Float16* __restrict__ out, int M, int K) {
    __shared__ _Float16 lds[2][10240];   // [buf][A 128*32 | B 192*32] = 40 KB

    int bid = blockIdx.x;
    int xcd = bid & 7, grp = bid >> 3;
    int mt = xcd + 8 * (grp >> 1);
    int nt = grp & 1;
    int m0 = mt * 128, n0 = nt * 160;
    int t = threadIdx.x;
    int lane = t & 63, w = t >> 6;
    int wr = w >> 1, wcn = (w & 1) * 80;

    f32x4 acc[4][5] = {};
    int NK = K >> 5;

    auto stage = [&](int buf, int k0) {
        #pragma unroll
        for (int q = 0; q < 2; ++q) {           // A: 512 slots (128 rows x 4)
            int slot = q * 256 + t;
            int row = slot >> 2;
            int ch = ((slot & 3) ^ ((row >> 1) & 3)) << 3;
            gload16(&A[(size_t)(m0 + row) * K + k0 + ch],
                    &lds[buf][(q * 256 + w * 64) * 8]);
        }
        #pragma unroll
        for (int q = 0; q < 3; ++q) {           // B: 768 slots (192 rows x 4)
            int slot = q * 256 + t;
            int row = slot >> 2;
            int ch = ((slot & 3) ^ ((row >> 1) & 3)) << 3;
            gload16(&Bp[(size_t)(n0 + row) * K + k0 + ch],
                    &lds[buf][4096 + (q * 256 + w * 64) * 8]);
        }
    };

    stage(0, 0);
    for (int kt = 0; kt < NK; ++kt) {
        int cur = kt & 1;
        if (kt + 1 < NK) {
            stage(cur ^ 1, (kt + 1) << 5);
            asm volatile("s_waitcnt vmcnt(5)" ::: "memory");   // stage kt landed
        } else {
            asm volatile("s_waitcnt vmcnt(0)" ::: "memory");
        }
        __builtin_amdgcn_s_barrier();
        __builtin_amdgcn_sched_barrier(0);

        int lr = lane & 15, hi = lane >> 4;
        half8 af[4], bf[5];
        #pragma unroll
        for (int i = 0; i < 4; ++i) {
            int row = wr * 64 + i * 16 + lr;
            int lk = (hi ^ ((row >> 1) & 3)) * 8;
            af[i] = *(const half8*)&lds[cur][row * 32 + lk];
        }
        #pragma unroll
        for (int j = 0; j < 5; ++j) {
            int row = wcn + j * 16 + lr;
            int lk = (hi ^ ((row >> 1) & 3)) * 8;
            bf[j] = *(const half8*)&lds[cur][4096 + row * 32 + lk];
        }
        #pragma unroll
        for (int i = 0; i < 4; ++i)
            #pragma unroll
            for (int j = 0; j < 5; ++j)
                acc[i][j] = __builtin_amdgcn_mfma_f32_16x16x32_f16(af[i], bf[j], acc[i][j], 0, 0, 0);

        __builtin_amdgcn_sched_barrier(0);
        __builtin_amdgcn_s_barrier();   // all reads of cur done before restage
    }
    __syncthreads();

    // epilogue: acc -> ct (128x160 f16, overlays both bufs) -> coalesced stores
    _Float16* ct = &lds[0][0];
    {
        int lr = lane & 15, lq = (lane >> 4) * 4;
        #pragma unroll
        for (int j = 0; j < 5; ++j) {
            int col = wcn + j * 16 + lr;
            int gcol = n0 + col;
            float bv = (gcol < 300) ? bias[gcol] : 0.f;
            #pragma unroll
            for (int i = 0; i < 4; ++i) {
                int rbase = wr * 64 + i * 16 + lq;
                #pragma unroll
                for (int q = 0; q < 4; ++q) {
                    float v = acc[i][j][q] + bv;
                    if (RELU) v = v > 0.f ? v : 0.f;
                    if (gcol >= 300) v = 0.f;
                    ct[(rbase + q) * 160 + col] = (_Float16)v;
                }
            }
        }
    }
    __syncthreads();
    if (OUT8) {
        unsigned char* o8 = (unsigned char*)out;
        #pragma unroll
        for (int r = 0; r < 10; ++r) {
            int idx = r * 256 + t;
            int row = idx / 20, c = idx - row * 20;
            half8 v = *(const half8*)&ct[row * 160 + c * 8];
            int w0 = __builtin_amdgcn_cvt_pk_fp8_f32((float)v[0], (float)v[1], 0, false);
            w0     = __builtin_amdgcn_cvt_pk_fp8_f32((float)v[2], (float)v[3], w0, true);
            int w1 = __builtin_amdgcn_cvt_pk_fp8_f32((float)v[4], (float)v[5], 0, false);
            w1     = __builtin_amdgcn_cvt_pk_fp8_f32((float)v[6], (float)v[7], w1, true);
            uint2 pack; pack.x = (unsigned)w0; pack.y = (unsigned)w1;
            *(uint2*)&o8[(size_t)(m0 + row) * HPAD + n0 + c * 8] = pack;
        }
    } else {
        #pragma unroll
        for (int r = 0; r < 10; ++r) {
            int idx = r * 256 + t;
            int row = idx / 20, c = idx - row * 20;
            half8 v = *(const half8*)&ct[row * 160 + c * 8];
            *(half8*)&out[(size_t)(m0 + row) * HPAD + n0 + c * 8] = v;
        }
    }
}

// ---------------- CSR build (natural node order) ----------------
__global__ __launch_bounds__(256) void hist_kernel(const int* __restrict__ dst,
                                                   int* __restrict__ counts) {
    int e = blockIdx.x * 256 + threadIdx.x;
    if (e < N_EDGES) atomicAdd(&counts[dst[e]], 1);
}

__global__ __launch_bounds__(256) void scan_block(const int* __restrict__ in,
                                                  int* __restrict__ partial,
                                                  int* __restrict__ bsum, int nb) {
    __shared__ int s[256];
    int b = blockIdx.x, t = threadIdx.x;
    int v = (b < nb) ? in[b * 256 + t] : 0;
    s[t] = v;
    __syncthreads();
    for (int o = 1; o < 256; o <<= 1) {
        int x = (t >= o) ? s[t - o] : 0;
        __syncthreads();
        s[t] += x;
        __syncthreads();
    }
    partial[b * 256 + t] = s[t] - v;      // exclusive
    if (t == 255 && bsum) bsum[b] = s[255];
}

__global__ __launch_bounds__(256) void add_offsets(const int* __restrict__ partial,
                                                   const int* __restrict__ boff,
                                                   int* __restrict__ rowptr) {
    int i = blockIdx.x * 256 + threadIdx.x;
    if (i < N_NODES) rowptr[i] = partial[i] + boff[i >> 8];
    if (i == 0) rowptr[N_NODES] = N_EDGES;
}

__global__ __launch_bounds__(256) void scatter_csr(const int* __restrict__ src,
                                                   const int* __restrict__ dst,
                                                   const int* __restrict__ rowptr,
                                                   int* __restrict__ cnt,
                                                   int2* __restrict__ se) {
    int e = blockIdx.x * 256 + threadIdx.x;
    if (e >= N_EDGES) return;
    int d = dst[e];
    int pos = atomicAdd(&cnt[d], 1);
    se[rowptr[d] + pos] = make_int2(src[e], e);
}

// ---------------- gather: z[d] = h[d] + sum_{s in row(d)} relu(h[src_s] + eh8[s])
// eh8 is fp8-e4m3 in CSR order (8B/edge-chunk) -> half the stream bytes.
// 320 thr = 8 node-slots x 40 half8 col-chunks. Batch-4 edges.
__global__ __launch_bounds__(320) void gather_z(
        const _Float16* __restrict__ h, const unsigned char* __restrict__ eh8,
        const int2* __restrict__ se, const int* __restrict__ rowptr,
        _Float16* __restrict__ z, int nblocks) {
    int t = threadIdx.x;
    int c = t % 40, ns = t / 40;
    for (int node = blockIdx.x * 8 + ns; node < N_NODES; node += nblocks * 8) {
        int r0 = rowptr[node], r1 = rowptr[node + 1];
        half8 hn = *(const half8*)&h[(size_t)node * HPAD + c * 8];
        half8 acc = {};
        for (int s = r0; s < r1; s += 4) {
            int nb = r1 - s;
            int idx[4];
            idx[0] = s;
            idx[1] = s + (1 < nb ? 1 : 0);
            idx[2] = s + (2 < nb ? 2 : 0);
            idx[3] = s + (3 < nb ? 3 : 0);
            half8 hv[4];
            uint2 ew[4];
            #pragma unroll
            for (int u = 0; u < 4; ++u) {
                int sp = se[idx[u]].x;
                hv[u] = *(const half8*)&h[(size_t)sp * HPAD + c * 8];
                ew[u] = *(const uint2*)&eh8[(size_t)idx[u] * HPAD + c * 8];
            }
            #pragma unroll
            for (int u = 0; u < 4; ++u) {
                f32x2 f01 = __builtin_amdgcn_cvt_pk_f32_fp8((int)ew[u].x, false);
                f32x2 f23 = __builtin_amdgcn_cvt_pk_f32_fp8((int)ew[u].x, true);
                f32x2 f45 = __builtin_amdgcn_cvt_pk_f32_fp8((int)ew[u].y, false);
                f32x2 f67 = __builtin_amdgcn_cvt_pk_f32_fp8((int)ew[u].y, true);
                fp16x2 e01 = __builtin_amdgcn_cvt_pkrtz(f01.x, f01.y);
                fp16x2 e23 = __builtin_amdgcn_cvt_pkrtz(f23.x, f23.y);
                fp16x2 e45 = __builtin_amdgcn_cvt_pkrtz(f45.x, f45.y);
                fp16x2 e67 = __builtin_amdgcn_cvt_pkrtz(f67.x, f67.y);
                half8 ev;
                ev[0] = (_Float16)e01.x; ev[1] = (_Float16)e01.y;
                ev[2] = (_Float16)e23.x; ev[3] = (_Float16)e23.y;
                ev[4] = (_Float16)e45.x; ev[5] = (_Float16)e45.y;
                ev[6] = (_Float16)e67.x; ev[7] = (_Float16)e67.y;
                half8 m = hv[u] + ev;
                #pragma unroll
                for (int j = 0; j < 8; ++j)
                    m[j] = m[j] > (_Float16)0 ? m[j] : (_Float16)0;
                if (u < nb) acc += m;
            }
        }
        half8 o = hn + acc;          // pad cols: 0 + 0 = 0
        *(half8*)&z[(size_t)node * HPAD + c * 8] = o;
    }
}

// ---------------- per-molecule sum pool (32 consecutive rows)
__global__ __launch_bounds__(128) void pool_kernel(const _Float16* __restrict__ h,
                                                   float* __restrict__ out, int add) {
    int b = blockIdx.x, t = threadIdx.x;
    if (t >= 75) return;
    float a0 = 0, a1 = 0, a2 = 0, a3 = 0;
    for (int r = 0; r < 32; ++r) {
        half4 v = *(const half4*)&h[(size_t)(b * 32 + r) * HPAD + t * 4];
        a0 += (float)v[0]; a1 += (float)v[1]; a2 += (float)v[2]; a3 += (float)v[3];
    }
    f32x4 o = {a0, a1, a2, a3};
    if (add) o += *(f32x4*)&out[b * 300 + t * 4];
    *(f32x4*)&out[b * 300 + t * 4] = o;
}

__global__ __launch_bounds__(256) void diff_kernel(float* __restrict__ reaction,
                                                   const float* __restrict__ reactants,
                                                   const float* __restrict__ products, int n) {
    int i = blockIdx.x * 256 + threadIdx.x;
    if (i < n) reaction[i] = reactants[i] - products[i];
}

extern "C" void kernel_launch(void* const* d_in, const int* in_sizes, int n_in,
                              void* d_out, int out_size, void* d_ws, size_t ws_size,
                              hipStream_t stream) {
    const float* x[3]   = {(const float*)d_in[0], (const float*)d_in[5],  (const float*)d_in[10]};
    const float* ein[3] = {(const float*)d_in[1], (const float*)d_in[6],  (const float*)d_in[11]};
    const int*   src[3] = {(const int*)d_in[2],   (const int*)d_in[7],    (const int*)d_in[12]};
    const int*   dst[3] = {(const int*)d_in[3],   (const int*)d_in[8],    (const int*)d_in[13]};
    const float* Wn = (const float*)d_in[15];
    const float* bn = (const float*)d_in[16];
    const float* We = (const float*)d_in[17];
    const float* be = (const float*)d_in[18];
    const float* W1 = (const float*)d_in[19];
    const float* b1 = (const float*)d_in[20];
    const float* W2 = (const float*)d_in[21];
    const float* b2 = (const float*)d_in[22];

    char* ws = (char*)d_ws;
    size_t off = 0;
    auto alloc = [&](size_t bytes) {
        char* p = ws + off; off += (bytes + 1023) & ~(size_t)1023; return p;
    };
    _Float16* h     = (_Float16*)alloc((size_t)N_NODES * HPAD * 2);     // 40 MiB
    _Float16* zbuf  = (_Float16*)alloc((size_t)N_NODES * HPAD * 2);     // 40 MiB
    _Float16* tbuf  = (_Float16*)alloc((size_t)N_NODES * HPAD * 2);     // 40 MiB
    unsigned char* ehcsr8 = (unsigned char*)alloc((size_t)N_EDGES * HPAD); // 40 MiB (fp8)
    int*      counts= (int*)alloc((size_t)N_NODES * 4);                 // \ contiguous
    int*      cnt   = (int*)alloc((size_t)N_NODES * 4);                 // /  memset pair
    int*      part  = (int*)alloc((size_t)N_NODES * 4);
    int*      bsum  = (int*)alloc(256 * 4);
    int*      bpart = (int*)alloc(256 * 4);
    int*      bzero = (int*)alloc(4);
    int*      rowptr= (int*)alloc((size_t)(N_NODES + 1) * 4);
    int2*     se    = (int2*)alloc((size_t)N_EDGES * 8);
    _Float16* Wt1   = (_Float16*)alloc((size_t)3 * 384 * HPAD * 2);
    _Float16* Wt2   = (_Float16*)alloc((size_t)3 * 384 * HPAD * 2);
    _Float16* Wnt   = (_Float16*)alloc((size_t)384 * 64 * 2);
    _Float16* Wet   = (_Float16*)alloc((size_t)384 * 32 * 2);
    // overlays (both dead before their hosts are written):
    _Float16* xh    = (_Float16*)zbuf;   // consumed by node-proj GEMM before gather writes zbuf
    _Float16* ecsr  = (_Float16*)tbuf;   // consumed by eh-GEMM before GEMM1 writes tbuf

    if (off > ws_size) return;   // graceful diagnostic failure if ws too small

    for (int l = 0; l < 3; ++l) {
        prepack_w<<<(384 * HPAD + 255) / 256, 256, 0, stream>>>(W1 + l * 90000, Wt1 + l * 384 * HPAD, HPAD, 300);
        prepack_w<<<(384 * HPAD + 255) / 256, 256, 0, stream>>>(W2 + l * 90000, Wt2 + l * 384 * HPAD, HPAD, 300);
    }
    prepack_w<<<(384 * 64 + 255) / 256, 256, 0, stream>>>(Wn, Wnt, 64, 64);
    prepack_w<<<(384 * 32 + 255) / 256, 256, 0, stream>>>(We, Wet, 32, 16);
    hipMemsetAsync(bzero, 0, 4, stream);

    float* outp      = (float*)d_out;
    float* reaction  = outp;
    float* reactants = outp + (size_t)BB * HDIM;
    float* products  = outp + (size_t)2 * BB * HDIM;

    const int EG = (N_EDGES + 255) / 256;
    for (int g = 0; g < 3; ++g) {
        // node projection: h = relu(x @ Wn + bn)
        cvt_x<<<(N_NODES * 64 + 255) / 256, 256, 0, stream>>>(x[g], xh, N_NODES * 64);
        gemm_f16<true, false><<<512 * 2, 256, 0, stream>>>(xh, Wnt, bn, h, N_NODES, 64);

        // CSR build (incoming edges per node), natural node order
        hipMemsetAsync(counts, 0, (size_t)2 * N_NODES * 4, stream);   // counts + cnt
        hist_kernel<<<EG, 256, 0, stream>>>(dst[g], counts);
        scan_block<<<256, 256, 0, stream>>>(counts, part, bsum, 256);
        scan_block<<<1, 256, 0, stream>>>(bsum, bpart, bzero, 1);
        add_offsets<<<256, 256, 0, stream>>>(part, bpart, rowptr);
        scatter_csr<<<EG, 256, 0, stream>>>(src[g], dst[g], rowptr, cnt, se);

        // edge projection once per graph, in CSR order, fp8 out: eh8 = ecsr @ We + be
        cvt_e_csr<<<(N_EDGES * 32 + 255) / 256, 256, 0, stream>>>(ein[g], se, ecsr);
        gemm_f16<false, true><<<1024 * 2, 256, 0, stream>>>(ecsr, Wet, be, (_Float16*)ehcsr8, N_EDGES, 32);

        for (int l = 0; l < 3; ++l) {
            gather_z<<<2048, 320, 0, stream>>>(h, ehcsr8, se, rowptr, zbuf, 2048);
            // t = relu(z @ W1[l] + b1[l])
            gemm_f16<true, false><<<512 * 2, 256, 0, stream>>>(zbuf, Wt1 + l * 384 * HPAD, b1 + l * 300, tbuf, N_NODES, HPAD);
            // h = t @ W2[l] + b2[l]  (+relu if l<2)
            if (l < 2)
                gemm_f16<true , false><<<512 * 2, 256, 0, stream>>>(tbuf, Wt2 + l * 384 * HPAD, b2 + l * 300, h, N_NODES, HPAD);
            else
                gemm_f16<false, false><<<512 * 2, 256, 0, stream>>>(tbuf, Wt2 + l * 384 * HPAD, b2 + l * 300, h, N_NODES, HPAD);
        }
        if (g == 0)      pool_kernel<<<BB, 128, 0, stream>>>(h, reactants, 0);
        else if (g == 1) pool_kernel<<<BB, 128, 0, stream>>>(h, reactants, 1);
        else             pool_kernel<<<BB, 128, 0, stream>>>(h, products, 0);
    }
    diff_kernel<<<((BB * HDIM) + 255) / 256, 256, 0, stream>>>(reaction, reactants, products, BB * HDIM);
}

// Round 18
// 955.898 us; speedup vs baseline: 1.5749x; 1.0267x over previous
//
#include <hip/hip_runtime.h>

typedef _Float16 half8 __attribute__((ext_vector_type(8)));
typedef _Float16 half4 __attribute__((ext_vector_type(4)));
typedef __fp16   fp16x2 __attribute__((ext_vector_type(2)));
typedef float    f32x4 __attribute__((ext_vector_type(4)));
typedef float    f32x2 __attribute__((ext_vector_type(2)));

#define N_NODES 65536
#define N_EDGES 131072
#define BB      2048
#define HDIM    300
#define HPAD    320   // K padded to multiple of 32

// ---------------- prepack: dst[384][Kpad] = W[k][n]  (B^T panel, zero-padded)
__global__ __launch_bounds__(256) void prepack_w(const float* __restrict__ src,
                                                 _Float16* __restrict__ dst,
                                                 int Kpad, int Kreal) {
    int idx = blockIdx.x * 256 + threadIdx.x;
    int n = idx / Kpad, k = idx - n * Kpad;
    if (n >= 384) return;
    float v = (n < 300 && k < Kreal) ? src[k * 300 + n] : 0.f;
    dst[idx] = (_Float16)v;
}

__global__ __launch_bounds__(256) void cvt_x(const float* __restrict__ x,
                                             _Float16* __restrict__ xh, int n) {
    int i = blockIdx.x * 256 + threadIdx.x;
    if (i < n) xh[i] = (_Float16)x[i];
}

// edge feats -> f16, permuted into CSR order, zero-padded to 32 cols
__global__ __launch_bounds__(256) void cvt_e_csr(const float* __restrict__ ein,
                                                 const int2* __restrict__ se,
                                                 _Float16* __restrict__ ecsr) {
    int i = blockIdx.x * 256 + threadIdx.x;
    if (i >= N_EDGES * 32) return;
    int k = i & 31, s = i >> 5;
    int e = se[s].y;
    ecsr[i] = (_Float16)(k < 16 ? ein[(size_t)e * 16 + k] : 0.f);
}

__device__ __forceinline__ void gload16(const _Float16* g, _Float16* l) {
    __builtin_amdgcn_global_load_lds(
        (const __attribute__((address_space(1))) void*)g,
        (__attribute__((address_space(3))) void*)l, 16, 0, 0);
}

// ---------------- MFMA GEMM: out[M][320] = op( A[M][K] @ Bp^T ) + bias
// 2x160 N-tiling, block = 128x160, 4 waves of 64x80, acc[4][5]=80 f32.
// A staged 128 rows + B staged 192 rows, 2-buffer, counted vmcnt(5), XOR swizzle.
// OUT8: epilogue emits OCP fp8-e4m3 (eh stream halved).
// POOL: last-layer variant — skips the global h write and instead emits
// per-molecule column sums (4 molecules x 160 cols per block) to pool_out.
template <bool RELU, bool OUT8, bool POOL>
__global__ __launch_bounds__(256, 3) void gemm_f16(
        const _Float16* __restrict__ A,
        const _Float16* __restrict__ Bp, const float* __restrict__ bias,
        _Float16* __restrict__ out, int M, int K,
        float* __restrict__ pool_out, int pool_add) {
    __shared__ _Float16 lds[2][10240];   // [buf][A 128*32 | B 192*32] = 40 KB

    int bid = blockIdx.x;
    int xcd = bid & 7, grp = bid >> 3;
    int mt = xcd + 8 * (grp >> 1);
    int nt = grp & 1;
    int m0 = mt * 128, n0 = nt * 160;
    int t = threadIdx.x;
    int lane = t & 63, w = t >> 6;
    int wr = w >> 1, wcn = (w & 1) * 80;

    f32x4 acc[4][5] = {};
    int NK = K >> 5;

    auto stage = [&](int buf, int k0) {
        #pragma unroll
        for (int q = 0; q < 2; ++q) {           // A: 512 slots (128 rows x 4)
            int slot = q * 256 + t;
            int row = slot >> 2;
            int ch = ((slot & 3) ^ ((row >> 1) & 3)) << 3;
            gload16(&A[(size_t)(m0 + row) * K + k0 + ch],
                    &lds[buf][(q * 256 + w * 64) * 8]);
        }
        #pragma unroll
        for (int q = 0; q < 3; ++q) {           // B: 768 slots (192 rows x 4)
            int slot = q * 256 + t;
            int row = slot >> 2;
            int ch = ((slot & 3) ^ ((row >> 1) & 3)) << 3;
            gload16(&Bp[(size_t)(n0 + row) * K + k0 + ch],
                    &lds[buf][4096 + (q * 256 + w * 64) * 8]);
        }
    };

    stage(0, 0);
    for (int kt = 0; kt < NK; ++kt) {
        int cur = kt & 1;
        if (kt + 1 < NK) {
            stage(cur ^ 1, (kt + 1) << 5);
            asm volatile("s_waitcnt vmcnt(5)" ::: "memory");   // stage kt landed
        } else {
            asm volatile("s_waitcnt vmcnt(0)" ::: "memory");
        }
        __builtin_amdgcn_s_barrier();
        __builtin_amdgcn_sched_barrier(0);

        int lr = lane & 15, hi = lane >> 4;
        half8 af[4], bf[5];
        #pragma unroll
        for (int i = 0; i < 4; ++i) {
            int row = wr * 64 + i * 16 + lr;
            int lk = (hi ^ ((row >> 1) & 3)) * 8;
            af[i] = *(const half8*)&lds[cur][row * 32 + lk];
        }
        #pragma unroll
        for (int j = 0; j < 5; ++j) {
            int row = wcn + j * 16 + lr;
            int lk = (hi ^ ((row >> 1) & 3)) * 8;
            bf[j] = *(const half8*)&lds[cur][4096 + row * 32 + lk];
        }
        #pragma unroll
        for (int i = 0; i < 4; ++i)
            #pragma unroll
            for (int j = 0; j < 5; ++j)
                acc[i][j] = __builtin_amdgcn_mfma_f32_16x16x32_f16(af[i], bf[j], acc[i][j], 0, 0, 0);

        __builtin_amdgcn_sched_barrier(0);
        __builtin_amdgcn_s_barrier();   // all reads of cur done before restage
    }
    __syncthreads();

    // epilogue: acc -> ct (128x160 f16, overlays both bufs)
    _Float16* ct = &lds[0][0];
    {
        int lr = lane & 15, lq = (lane >> 4) * 4;
        #pragma unroll
        for (int j = 0; j < 5; ++j) {
            int col = wcn + j * 16 + lr;
            int gcol = n0 + col;
            float bv = (gcol < 300) ? bias[gcol] : 0.f;
            #pragma unroll
            for (int i = 0; i < 4; ++i) {
                int rbase = wr * 64 + i * 16 + lq;
                #pragma unroll
                for (int q = 0; q < 4; ++q) {
                    float v = acc[i][j][q] + bv;
                    if (RELU) v = v > 0.f ? v : 0.f;
                    if (gcol >= 300) v = 0.f;
                    ct[(rbase + q) * 160 + col] = (_Float16)v;
                }
            }
        }
    }
    __syncthreads();
    if (POOL) {
        // per-molecule column sums: 4 molecules (32 rows each) x 160 cols.
        // Blocks own disjoint (molecule, col-range) -> no atomics needed.
        for (int idx = t; idx < 4 * 160; idx += 256) {
            int mol = idx / 160, col = idx - mol * 160;
            int gcol = n0 + col;
            if (gcol >= 300) continue;
            float s = 0.f;
            #pragma unroll
            for (int r = 0; r < 32; ++r)
                s += (float)ct[(mol * 32 + r) * 160 + col];
            float* p = &pool_out[(size_t)(mt * 4 + mol) * 300 + gcol];
            if (pool_add) s += *p;
            *p = s;
        }
    } else if (OUT8) {
        unsigned char* o8 = (unsigned char*)out;
        #pragma unroll
        for (int r = 0; r < 10; ++r) {
            int idx = r * 256 + t;
            int row = idx / 20, c = idx - row * 20;
            half8 v = *(const half8*)&ct[row * 160 + c * 8];
            int w0 = __builtin_amdgcn_cvt_pk_fp8_f32((float)v[0], (float)v[1], 0, false);
            w0     = __builtin_amdgcn_cvt_pk_fp8_f32((float)v[2], (float)v[3], w0, true);
            int w1 = __builtin_amdgcn_cvt_pk_fp8_f32((float)v[4], (float)v[5], 0, false);
            w1     = __builtin_amdgcn_cvt_pk_fp8_f32((float)v[6], (float)v[7], w1, true);
            uint2 pack; pack.x = (unsigned)w0; pack.y = (unsigned)w1;
            *(uint2*)&o8[(size_t)(m0 + row) * HPAD + n0 + c * 8] = pack;
        }
    } else {
        #pragma unroll
        for (int r = 0; r < 10; ++r) {
            int idx = r * 256 + t;
            int row = idx / 20, c = idx - row * 20;
            half8 v = *(const half8*)&ct[row * 160 + c * 8];
            *(half8*)&out[(size_t)(m0 + row) * HPAD + n0 + c * 8] = v;
        }
    }
}

// ---------------- CSR build (natural node order) ----------------
__global__ __launch_bounds__(256) void hist_kernel(const int* __restrict__ dst,
                                                   int* __restrict__ counts) {
    int e = blockIdx.x * 256 + threadIdx.x;
    if (e < N_EDGES) atomicAdd(&counts[dst[e]], 1);
}

__global__ __launch_bounds__(256) void scan_block(const int* __restrict__ in,
                                                  int* __restrict__ partial,
                                                  int* __restrict__ bsum, int nb) {
    __shared__ int s[256];
    int b = blockIdx.x, t = threadIdx.x;
    int v = (b < nb) ? in[b * 256 + t] : 0;
    s[t] = v;
    __syncthreads();
    for (int o = 1; o < 256; o <<= 1) {
        int x = (t >= o) ? s[t - o] : 0;
        __syncthreads();
        s[t] += x;
        __syncthreads();
    }
    partial[b * 256 + t] = s[t] - v;      // exclusive
    if (t == 255 && bsum) bsum[b] = s[255];
}

__global__ __launch_bounds__(256) void add_offsets(const int* __restrict__ partial,
                                                   const int* __restrict__ boff,
                                                   int* __restrict__ rowptr) {
    int i = blockIdx.x * 256 + threadIdx.x;
    if (i < N_NODES) rowptr[i] = partial[i] + boff[i >> 8];
    if (i == 0) rowptr[N_NODES] = N_EDGES;
}

__global__ __launch_bounds__(256) void scatter_csr(const int* __restrict__ src,
                                                   const int* __restrict__ dst,
                                                   const int* __restrict__ rowptr,
                                                   int* __restrict__ cnt,
                                                   int2* __restrict__ se) {
    int e = blockIdx.x * 256 + threadIdx.x;
    if (e >= N_EDGES) return;
    int d = dst[e];
    int pos = atomicAdd(&cnt[d], 1);
    se[rowptr[d] + pos] = make_int2(src[e], e);
}

// ---------------- gather: z[d] = h[d] + sum_{s in row(d)} relu(h[src_s] + eh8[s])
// eh8 is fp8-e4m3 in CSR order (8B/edge-chunk) -> half the stream bytes.
// 320 thr = 8 node-slots x 40 half8 col-chunks. Batch-4 edges.
__global__ __launch_bounds__(320) void gather_z(
        const _Float16* __restrict__ h, const unsigned char* __restrict__ eh8,
        const int2* __restrict__ se, const int* __restrict__ rowptr,
        _Float16* __restrict__ z, int nblocks) {
    int t = threadIdx.x;
    int c = t % 40, ns = t / 40;
    for (int node = blockIdx.x * 8 + ns; node < N_NODES; node += nblocks * 8) {
        int r0 = rowptr[node], r1 = rowptr[node + 1];
        half8 hn = *(const half8*)&h[(size_t)node * HPAD + c * 8];
        half8 acc = {};
        for (int s = r0; s < r1; s += 4) {
            int nb = r1 - s;
            int idx[4];
            idx[0] = s;
            idx[1] = s + (1 < nb ? 1 : 0);
            idx[2] = s + (2 < nb ? 2 : 0);
            idx[3] = s + (3 < nb ? 3 : 0);
            half8 hv[4];
            uint2 ew[4];
            #pragma unroll
            for (int u = 0; u < 4; ++u) {
                int sp = se[idx[u]].x;
                hv[u] = *(const half8*)&h[(size_t)sp * HPAD + c * 8];
                ew[u] = *(const uint2*)&eh8[(size_t)idx[u] * HPAD + c * 8];
            }
            #pragma unroll
            for (int u = 0; u < 4; ++u) {
                f32x2 f01 = __builtin_amdgcn_cvt_pk_f32_fp8((int)ew[u].x, false);
                f32x2 f23 = __builtin_amdgcn_cvt_pk_f32_fp8((int)ew[u].x, true);
                f32x2 f45 = __builtin_amdgcn_cvt_pk_f32_fp8((int)ew[u].y, false);
                f32x2 f67 = __builtin_amdgcn_cvt_pk_f32_fp8((int)ew[u].y, true);
                fp16x2 e01 = __builtin_amdgcn_cvt_pkrtz(f01.x, f01.y);
                fp16x2 e23 = __builtin_amdgcn_cvt_pkrtz(f23.x, f23.y);
                fp16x2 e45 = __builtin_amdgcn_cvt_pkrtz(f45.x, f45.y);
                fp16x2 e67 = __builtin_amdgcn_cvt_pkrtz(f67.x, f67.y);
                half8 ev;
                ev[0] = (_Float16)e01.x; ev[1] = (_Float16)e01.y;
                ev[2] = (_Float16)e23.x; ev[3] = (_Float16)e23.y;
                ev[4] = (_Float16)e45.x; ev[5] = (_Float16)e45.y;
                ev[6] = (_Float16)e67.x; ev[7] = (_Float16)e67.y;
                half8 m = hv[u] + ev;
                #pragma unroll
                for (int j = 0; j < 8; ++j)
                    m[j] = m[j] > (_Float16)0 ? m[j] : (_Float16)0;
                if (u < nb) acc += m;
            }
        }
        half8 o = hn + acc;          // pad cols: 0 + 0 = 0
        *(half8*)&z[(size_t)node * HPAD + c * 8] = o;
    }
}

__global__ __launch_bounds__(256) void diff_kernel(float* __restrict__ reaction,
                                                   const float* __restrict__ reactants,
                                                   const float* __restrict__ products, int n) {
    int i = blockIdx.x * 256 + threadIdx.x;
    if (i < n) reaction[i] = reactants[i] - products[i];
}

extern "C" void kernel_launch(void* const* d_in, const int* in_sizes, int n_in,
                              void* d_out, int out_size, void* d_ws, size_t ws_size,
                              hipStream_t stream) {
    const float* x[3]   = {(const float*)d_in[0], (const float*)d_in[5],  (const float*)d_in[10]};
    const float* ein[3] = {(const float*)d_in[1], (const float*)d_in[6],  (const float*)d_in[11]};
    const int*   src[3] = {(const int*)d_in[2],   (const int*)d_in[7],    (const int*)d_in[12]};
    const int*   dst[3] = {(const int*)d_in[3],   (const int*)d_in[8],    (const int*)d_in[13]};
    const float* Wn = (const float*)d_in[15];
    const float* bn = (const float*)d_in[16];
    const float* We = (const float*)d_in[17];
    const float* be = (const float*)d_in[18];
    const float* W1 = (const float*)d_in[19];
    const float* b1 = (const float*)d_in[20];
    const float* W2 = (const float*)d_in[21];
    const float* b2 = (const float*)d_in[22];

    char* ws = (char*)d_ws;
    size_t off = 0;
    auto alloc = [&](size_t bytes) {
        char* p = ws + off; off += (bytes + 1023) & ~(size_t)1023; return p;
    };
    _Float16* h     = (_Float16*)alloc((size_t)N_NODES * HPAD * 2);     // 40 MiB
    _Float16* zbuf  = (_Float16*)alloc((size_t)N_NODES * HPAD * 2);     // 40 MiB
    _Float16* tbuf  = (_Float16*)alloc((size_t)N_NODES * HPAD * 2);     // 40 MiB
    unsigned char* ehcsr8 = (unsigned char*)alloc((size_t)N_EDGES * HPAD); // 40 MiB (fp8)
    int*      counts= (int*)alloc((size_t)N_NODES * 4);                 // \ contiguous
    int*      cnt   = (int*)alloc((size_t)N_NODES * 4);                 // /  memset pair
    int*      part  = (int*)alloc((size_t)N_NODES * 4);
    int*      bsum  = (int*)alloc(256 * 4);
    int*      bpart = (int*)alloc(256 * 4);
    int*      bzero = (int*)alloc(4);
    int*      rowptr= (int*)alloc((size_t)(N_NODES + 1) * 4);
    int2*     se    = (int2*)alloc((size_t)N_EDGES * 8);
    _Float16* Wt1   = (_Float16*)alloc((size_t)3 * 384 * HPAD * 2);
    _Float16* Wt2   = (_Float16*)alloc((size_t)3 * 384 * HPAD * 2);
    _Float16* Wnt   = (_Float16*)alloc((size_t)384 * 64 * 2);
    _Float16* Wet   = (_Float16*)alloc((size_t)384 * 32 * 2);
    // overlays (both dead before their hosts are written):
    _Float16* xh    = (_Float16*)zbuf;   // consumed by node-proj GEMM before gather writes zbuf
    _Float16* ecsr  = (_Float16*)tbuf;   // consumed by eh-GEMM before GEMM1 writes tbuf

    if (off > ws_size) return;   // graceful diagnostic failure if ws too small

    for (int l = 0; l < 3; ++l) {
        prepack_w<<<(384 * HPAD + 255) / 256, 256, 0, stream>>>(W1 + l * 90000, Wt1 + l * 384 * HPAD, HPAD, 300);
        prepack_w<<<(384 * HPAD + 255) / 256, 256, 0, stream>>>(W2 + l * 90000, Wt2 + l * 384 * HPAD, HPAD, 300);
    }
    prepack_w<<<(384 * 64 + 255) / 256, 256, 0, stream>>>(Wn, Wnt, 64, 64);
    prepack_w<<<(384 * 32 + 255) / 256, 256, 0, stream>>>(We, Wet, 32, 16);
    hipMemsetAsync(bzero, 0, 4, stream);

    float* outp      = (float*)d_out;
    float* reaction  = outp;
    float* reactants = outp + (size_t)BB * HDIM;
    float* products  = outp + (size_t)2 * BB * HDIM;

    const int EG = (N_EDGES + 255) / 256;
    for (int g = 0; g < 3; ++g) {
        // node projection: h = relu(x @ Wn + bn)
        cvt_x<<<(N_NODES * 64 + 255) / 256, 256, 0, stream>>>(x[g], xh, N_NODES * 64);
        gemm_f16<true, false, false><<<512 * 2, 256, 0, stream>>>(xh, Wnt, bn, h, N_NODES, 64, nullptr, 0);

        // CSR build (incoming edges per node), natural node order
        hipMemsetAsync(counts, 0, (size_t)2 * N_NODES * 4, stream);   // counts + cnt
        hist_kernel<<<EG, 256, 0, stream>>>(dst[g], counts);
        scan_block<<<256, 256, 0, stream>>>(counts, part, bsum, 256);
        scan_block<<<1, 256, 0, stream>>>(bsum, bpart, bzero, 1);
        add_offsets<<<256, 256, 0, stream>>>(part, bpart, rowptr);
        scatter_csr<<<EG, 256, 0, stream>>>(src[g], dst[g], rowptr, cnt, se);

        // edge projection once per graph, in CSR order, fp8 out: eh8 = ecsr @ We + be
        cvt_e_csr<<<(N_EDGES * 32 + 255) / 256, 256, 0, stream>>>(ein[g], se, ecsr);
        gemm_f16<false, true, false><<<1024 * 2, 256, 0, stream>>>(ecsr, Wet, be, (_Float16*)ehcsr8, N_EDGES, 32, nullptr, 0);

        float* ptarget = (g == 2) ? products : reactants;
        int    padd    = (g == 1) ? 1 : 0;
        for (int l = 0; l < 3; ++l) {
            gather_z<<<2048, 320, 0, stream>>>(h, ehcsr8, se, rowptr, zbuf, 2048);
            // t = relu(z @ W1[l] + b1[l])
            gemm_f16<true, false, false><<<512 * 2, 256, 0, stream>>>(zbuf, Wt1 + l * 384 * HPAD, b1 + l * 300, tbuf, N_NODES, HPAD, nullptr, 0);
            // h = t @ W2[l] + b2[l]  (+relu if l<2); last layer fuses the pool
            if (l < 2)
                gemm_f16<true , false, false><<<512 * 2, 256, 0, stream>>>(tbuf, Wt2 + l * 384 * HPAD, b2 + l * 300, h, N_NODES, HPAD, nullptr, 0);
            else
                gemm_f16<false, false, true ><<<512 * 2, 256, 0, stream>>>(tbuf, Wt2 + l * 384 * HPAD, b2 + l * 300, h, N_NODES, HPAD, ptarget, padd);
        }
    }
    diff_kernel<<<((BB * HDIM) + 255) / 256, 256, 0, stream>>>(reaction, reactants, products, BB * HDIM);
}